// Round 5
// baseline (142.792 us; speedup 1.0000x reference)
//
#include <hip/hip_runtime.h>
#include <math.h>

// x:      [4,1024,768] fp32 -> bf16
// w_qkv:  [768,2304]   fp32 -> bf16 transposed [2304,768]
// w_out:  [768,768]    fp32 -> bf16 transposed [768,768]
// b_out:  [768]        fp32
// out:    [4,1024,768] fp32
// HEADS=12, DH=64.  Q pre-scaled by 0.125*log2(e) -> softmax in exp2 domain.

typedef __attribute__((ext_vector_type(8))) __bf16 bf16x8;
typedef __attribute__((ext_vector_type(4))) float f32x4;
typedef __attribute__((ext_vector_type(16))) float f32x16;
typedef unsigned short u16;
typedef unsigned int u32;

#define ZERO16 {0,0,0,0,0,0,0,0,0,0,0,0,0,0,0,0}

__device__ __forceinline__ u16 f2bf(float f) {
    union { float f; unsigned u; } v; v.f = f;
    unsigned r = v.u + 0x7FFF + ((v.u >> 16) & 1);   // RNE
    return (u16)(r >> 16);
}

__device__ __forceinline__ u32 cvtpk(float lo, float hi) {
    u32 r;
    asm("v_cvt_pk_bf16_f32 %0, %1, %2" : "=v"(r) : "v"(lo), "v"(hi));
    return r;
}
// cross-half (lane ^ 32) exchange via shfl (defined semantics, no alias hazard)
__device__ __forceinline__ float xhalf_max(float x) {
    float o = __shfl_xor(x, 32);
    return fmaxf(x, o);
}
__device__ __forceinline__ float xhalf_sum(float x) {
    float o = __shfl_xor(x, 32);
    return x + o;
}

// ---------------------------------------------------------------------------
__global__ void convert_x(const float* __restrict__ in, u16* __restrict__ out, int n4) {
    int i = blockIdx.x * blockDim.x + threadIdx.x;
    if (i < n4) {
        float4 v = reinterpret_cast<const float4*>(in)[i];
        union { u16 s[4]; int2 p; } o;
        o.s[0] = f2bf(v.x); o.s[1] = f2bf(v.y); o.s[2] = f2bf(v.z); o.s[3] = f2bf(v.w);
        reinterpret_cast<int2*>(out)[i] = o.p;
    }
}

__global__ __launch_bounds__(256) void transpose_convert(const float* __restrict__ in,
                                                         u16* __restrict__ out,
                                                         int R, int C) {
    __shared__ float T[32][33];
    const int tx = threadIdx.x & 31;
    const int ty = threadIdx.x >> 5;
    const int c0 = blockIdx.x * 32;
    const int r0 = blockIdx.y * 32;
#pragma unroll
    for (int p = 0; p < 4; ++p) {
        int ry = ty + p * 8;
        T[ry][tx] = in[(size_t)(r0 + ry) * C + c0 + tx];
    }
    __syncthreads();
#pragma unroll
    for (int p = 0; p < 4; ++p) {
        int cy = ty + p * 8;
        out[(size_t)(c0 + cy) * R + r0 + tx] = f2bf(T[tx][cy]);
    }
}

// ---------------------------------------------------------------------------
// GEMM1: qkv = x_bf16 @ w_qkv (via wqkvT), scatter Q(scaled)/K [bh][n][d],
// V transposed [bh][d][n].
// ---------------------------------------------------------------------------
__global__ __launch_bounds__(256) void gemm_qkv(const u16* __restrict__ A,
                                                const u16* __restrict__ BT,
                                                u16* __restrict__ Qb,
                                                u16* __restrict__ Kb,
                                                u16* __restrict__ Vt) {
    __shared__ u16 As[128][40];
    __shared__ u16 Bs[128][40];
    const int tid = threadIdx.x;
    const int lane = tid & 63;
    const int w = tid >> 6;
    const int wm = w >> 1, wn = w & 1;
    const int lr = lane & 15;
    const int lk = lane >> 4;
    const int row0 = blockIdx.y * 128;
    const int col0 = blockIdx.x * 128;

    f32x4 acc[4][4];
#pragma unroll
    for (int mi = 0; mi < 4; ++mi)
#pragma unroll
        for (int nj = 0; nj < 4; ++nj) acc[mi][nj] = (f32x4){0.f, 0.f, 0.f, 0.f};

    for (int k0 = 0; k0 < 768; k0 += 32) {
#pragma unroll
        for (int l = 0; l < 2; ++l) {
            int idx = tid + l * 256;
            int r = idx >> 2;
            int cg = idx & 3;
            *reinterpret_cast<int4*>(&As[r][cg * 8]) =
                *reinterpret_cast<const int4*>(&A[(size_t)(row0 + r) * 768 + k0 + cg * 8]);
            *reinterpret_cast<int4*>(&Bs[r][cg * 8]) =
                *reinterpret_cast<const int4*>(&BT[(size_t)(col0 + r) * 768 + k0 + cg * 8]);
        }
        __syncthreads();
        bf16x8 af[4], bfr[4];
#pragma unroll
        for (int mi = 0; mi < 4; ++mi)
            af[mi] = *reinterpret_cast<const bf16x8*>(&As[wm * 64 + mi * 16 + lr][lk * 8]);
#pragma unroll
        for (int nj = 0; nj < 4; ++nj)
            bfr[nj] = *reinterpret_cast<const bf16x8*>(&Bs[wn * 64 + nj * 16 + lr][lk * 8]);
#pragma unroll
        for (int mi = 0; mi < 4; ++mi)
#pragma unroll
            for (int nj = 0; nj < 4; ++nj)
                acc[mi][nj] = __builtin_amdgcn_mfma_f32_16x16x32_bf16(af[mi], bfr[nj], acc[mi][nj], 0, 0, 0);
        __syncthreads();
    }

    const int which = col0 / 768;
    const int cb = col0 - which * 768;
#pragma unroll
    for (int mi = 0; mi < 4; ++mi) {
#pragma unroll
        for (int i = 0; i < 4; ++i) {
            int r = row0 + wm * 64 + mi * 16 + lk * 4 + i;
            int b = r >> 10, n = r & 1023;
#pragma unroll
            for (int nj = 0; nj < 4; ++nj) {
                int cw = cb + wn * 64 + nj * 16 + lr;
                int h = cw >> 6, d = cw & 63;
                int bh = b * 12 + h;
                float val = acc[mi][nj][i];
                if (which == 0)      Qb[((size_t)bh * 1024 + n) * 64 + d] = f2bf(val * 0.18033688f); // 0.125*log2(e)
                else if (which == 1) Kb[((size_t)bh * 1024 + n) * 64 + d] = f2bf(val);
                else                 Vt[((size_t)bh * 64 + d) * 1024 + n] = f2bf(val);
            }
        }
    }
}

// ---------------------------------------------------------------------------
// Flash attention, swapped-operand 32x32x16 MFMA.
// Block = 4 waves: wave w -> qsub = w&1 (32 q-rows), half = w>>1 (KV parity).
// K/V staged cooperatively through XOR-swizzled LDS (coalesced global loads,
// reg-staged T14 pipeline: issue loads(it+1) -> compute(it) -> barrier ->
// ds_write -> barrier).  Merge buffers alias the staging LDS.
// ---------------------------------------------------------------------------
#define GETO(dt, r) ((dt) == 0 ? o0[r] : o1[r])

__global__ __launch_bounds__(256) void attn_mfma(const u16* __restrict__ Qb,
                                                 const u16* __restrict__ Kb,
                                                 const u16* __restrict__ Vt,
                                                 u16* __restrict__ attn_out) {
    __shared__ __align__(16) char smem[32768];
    char* KsBy = smem;                       // K tile  [128 keys][64 d] u16, row=128B, col16 ^= row&7
    char* VsBy = smem + 16384;               // Vt tile [64 d][128 keys] u16, row=256B, col16 ^= row&15
    // merge views (alias staging; only used after the final read-barrier)
    float* OtM = (float*)smem;               // [2][64][33]  (16896 B)
    float* Lm  = (float*)(smem + 16896);     // [2][32]
    float* Ll  = (float*)(smem + 17152);     // [2][32]
    u16*   Os  = (u16*)(smem + 17408);       // [2][32][72]  (9216 B)

    const int tid = threadIdx.x;
    const int lane = tid & 63;
    const int w = tid >> 6;
    const int qsub = w & 1;
    const int half = w >> 1;
    const int l31 = lane & 31;
    const int hi = lane >> 5;

    // XCD swizzle: 96 consecutive remapped ids per XCD -> 6 bh per XCD L2
    const int bid = blockIdx.x;
    const int lin = (bid & 7) * 96 + (bid >> 3);
    const int qt = lin & 15;
    const int bh = lin >> 4;

    const u16* Qh = Qb + (size_t)bh * 65536;
    const u16* Kh = Kb + (size_t)bh * 65536;
    const u16* Vh = Vt + (size_t)bh * 65536;
    const int q0 = qt * 64 + qsub * 32;

    // Q fragments (B-operand): lane: col=q0+l31, k = kt*16 + hi*8 + j
    const u16* qbase = Qh + (size_t)(q0 + l31) * 64 + hi * 8;
    bf16x8 qf[4];
#pragma unroll
    for (int kt = 0; kt < 4; ++kt)
        qf[kt] = *reinterpret_cast<const bf16x8*>(qbase + kt * 16);

    f32x16 o0 = ZERO16, o1 = ZERO16;   // O^T: rows d, col q=l31
    float m = -1e30f, l = 0.f;

    // ---- staging helpers (coalesced global -> regs -> swizzled LDS) ----
    int4 kreg[4], vreg[4];
#define STAGE_LOAD(KVA)                                                       \
    {                                                                         \
        _Pragma("unroll")                                                     \
        for (int p = 0; p < 4; ++p) {                                         \
            int c = p * 256 + tid;                                            \
            int kr = c >> 3, kc = c & 7;                                      \
            kreg[p] = *reinterpret_cast<const int4*>(&Kh[(size_t)((KVA) + kr) * 64 + kc * 8]); \
            int vr = c >> 4, vc = c & 15;                                     \
            vreg[p] = *reinterpret_cast<const int4*>(&Vh[(size_t)vr * 1024 + (KVA) + vc * 8]); \
        }                                                                     \
    }
#define STAGE_WRITE()                                                         \
    {                                                                         \
        _Pragma("unroll")                                                     \
        for (int p = 0; p < 4; ++p) {                                         \
            int c = p * 256 + tid;                                            \
            int kr = c >> 3, kc = c & 7;                                      \
            *reinterpret_cast<int4*>(KsBy + kr * 128 + ((kc ^ (kr & 7)) * 16)) = kreg[p]; \
            int vr = c >> 4, vc = c & 15;                                     \
            *reinterpret_cast<int4*>(VsBy + vr * 256 + ((vc ^ (vr & 15)) * 16)) = vreg[p]; \
        }                                                                     \
    }

    // prologue: stage iter 0
    STAGE_LOAD(0);
    STAGE_WRITE();
    __syncthreads();

    for (int it = 0; it < 8; ++it) {
        // issue next tile's global loads early; latency hides under compute
        if (it < 7) STAGE_LOAD((it + 1) * 128);

        // K fragments (A-operand) from swizzled LDS: row = half*64 (+32) + l31
        const int krow = half * 64 + l31;
        const int kx = l31 & 7;
        bf16x8 kf0[4], kf1[4];
#pragma unroll
        for (int kt = 0; kt < 4; ++kt) {
            kf0[kt] = *reinterpret_cast<const bf16x8*>(KsBy + krow * 128 + (((2 * kt + hi) ^ kx) * 16));
            kf1[kt] = *reinterpret_cast<const bf16x8*>(KsBy + (krow + 32) * 128 + (((2 * kt + hi) ^ kx) * 16));
        }
        // V fragments (A-operand of PV): row = l31 (+32) = d, cols = this half's keys
        const int vx = l31 & 15;
        bf16x8 vf0[4], vf1[4];
#pragma unroll
        for (int ks = 0; ks < 4; ++ks) {
            vf0[ks] = *reinterpret_cast<const bf16x8*>(VsBy + l31 * 256 + (((half * 8 + 2 * ks + hi) ^ vx) * 16));
            vf1[ks] = *reinterpret_cast<const bf16x8*>(VsBy + (l31 + 32) * 256 + (((half * 8 + 2 * ks + hi) ^ vx) * 16));
        }

        // S^T = K Q (pre-scaled, exp2 domain)
        f32x16 s0 = ZERO16, s1 = ZERO16;
        __builtin_amdgcn_s_setprio(1);
#pragma unroll
        for (int kt = 0; kt < 4; ++kt) s0 = __builtin_amdgcn_mfma_f32_32x32x16_bf16(kf0[kt], qf[kt], s0, 0, 0, 0);
#pragma unroll
        for (int kt = 0; kt < 4; ++kt) s1 = __builtin_amdgcn_mfma_f32_32x32x16_bf16(kf1[kt], qf[kt], s1, 0, 0, 0);
        __builtin_amdgcn_s_setprio(0);

        // tile max (in-lane tree + one cross-half exchange)
        float mx[8];
#pragma unroll
        for (int i = 0; i < 8; ++i)
            mx[i] = fmaxf(fmaxf(s0[2*i], s0[2*i+1]), fmaxf(s1[2*i], s1[2*i+1]));
        float pmax = fmaxf(fmaxf(fmaxf(mx[0], mx[1]), fmaxf(mx[2], mx[3])),
                           fmaxf(fmaxf(mx[4], mx[5]), fmaxf(mx[6], mx[7])));
        pmax = xhalf_max(pmax);

        // defer-max rescale (T13, THR=8 in log2 units)
        if (!__all(pmax <= m + 8.f)) {
            float mn = fmaxf(m, pmax);
            float c = __builtin_amdgcn_exp2f(m - mn);
            m = mn; l *= c;
            o0 = o0 * c; o1 = o1 * c;
        }

        // P = exp2(S - m)
#pragma unroll
        for (int r = 0; r < 16; ++r) s0[r] = __builtin_amdgcn_exp2f(s0[r] - m);
#pragma unroll
        for (int r = 0; r < 16; ++r) s1[r] = __builtin_amdgcn_exp2f(s1[r] - m);
        float sm[8];
#pragma unroll
        for (int i = 0; i < 8; ++i)
            sm[i] = (s0[2*i] + s0[2*i+1]) + (s1[2*i] + s1[2*i+1]);
        float tsum = ((sm[0]+sm[1]) + (sm[2]+sm[3])) + ((sm[4]+sm[5]) + (sm[6]+sm[7]));
        l += xhalf_sum(tsum);

        // pack P -> bf16 B-fragments (cross-half exchange via shfl_xor(32))
        bf16x8 pb[4];
#define PACK_GROUP(S, G, OUT)                                           \
        {                                                               \
            u32 X0 = cvtpk(S[8*(G)+0], S[8*(G)+1]);                     \
            u32 X1 = cvtpk(S[8*(G)+2], S[8*(G)+3]);                     \
            u32 Y0 = cvtpk(S[8*(G)+4], S[8*(G)+5]);                     \
            u32 Y1 = cvtpk(S[8*(G)+6], S[8*(G)+7]);                     \
            u32 X0s = (u32)__shfl_xor((int)X0, 32);                     \
            u32 X1s = (u32)__shfl_xor((int)X1, 32);                     \
            u32 Y0s = (u32)__shfl_xor((int)Y0, 32);                     \
            u32 Y1s = (u32)__shfl_xor((int)Y1, 32);                     \
            union { u32 u[4]; bf16x8 v; } pk_;                          \
            pk_.u[0] = hi ? Y0s : X0;                                   \
            pk_.u[1] = hi ? Y1s : X1;                                   \
            pk_.u[2] = hi ? Y0 : X0s;                                   \
            pk_.u[3] = hi ? Y1 : X1s;                                   \
            OUT = pk_.v;                                                \
        }
        PACK_GROUP(s0, 0, pb[0]);
        PACK_GROUP(s0, 1, pb[1]);
        PACK_GROUP(s1, 0, pb[2]);
        PACK_GROUP(s1, 1, pb[3]);
#undef PACK_GROUP

        // O^T += V^T P
        __builtin_amdgcn_s_setprio(1);
#pragma unroll
        for (int ks = 0; ks < 4; ++ks) {
            o0 = __builtin_amdgcn_mfma_f32_32x32x16_bf16(vf0[ks], pb[ks], o0, 0, 0, 0);
            o1 = __builtin_amdgcn_mfma_f32_32x32x16_bf16(vf1[ks], pb[ks], o1, 0, 0, 0);
        }
        __builtin_amdgcn_s_setprio(0);

        __syncthreads();                 // all waves done READING Ks/Vs
        if (it < 7) {
            STAGE_WRITE();               // vmcnt auto-waited by compiler
            __syncthreads();             // tile (it+1) visible
        }
    }
#undef STAGE_LOAD
#undef STAGE_WRITE
    // staging LDS is dead from here (final barrier above) -> merge aliases it

    // merge the two KV-parity halves via LDS
    if (half == 1) {
#pragma unroll
        for (int dt = 0; dt < 2; ++dt)
#pragma unroll
            for (int r = 0; r < 16; ++r)
                OtM[((size_t)qsub * 64 + dt * 32 + (r & 3) + 8 * (r >> 2) + 4 * hi) * 33 + l31] = GETO(dt, r);
        Lm[qsub * 32 + l31] = m;
        Ll[qsub * 32 + l31] = l;
    }
    __syncthreads();
    if (half == 0) {
        float m2 = Lm[qsub * 32 + l31], l2 = Ll[qsub * 32 + l31];
        float mn = fmaxf(m, m2);
        float a = __builtin_amdgcn_exp2f(m - mn);
        float bsc = __builtin_amdgcn_exp2f(m2 - mn);
        float lm = l * a + l2 * bsc;
        float inv = 1.0f / lm;
        float av = a * inv, bv = bsc * inv;
#pragma unroll
        for (int dt = 0; dt < 2; ++dt)
#pragma unroll
            for (int rq = 0; rq < 4; ++rq) {
                int d0 = dt * 32 + 8 * rq + 4 * hi;
                float v0 = GETO(dt, rq * 4 + 0) * av + OtM[((size_t)qsub * 64 + d0 + 0) * 33 + l31] * bv;
                float v1 = GETO(dt, rq * 4 + 1) * av + OtM[((size_t)qsub * 64 + d0 + 1) * 33 + l31] * bv;
                float v2 = GETO(dt, rq * 4 + 2) * av + OtM[((size_t)qsub * 64 + d0 + 2) * 33 + l31] * bv;
                float v3 = GETO(dt, rq * 4 + 3) * av + OtM[((size_t)qsub * 64 + d0 + 3) * 33 + l31] * bv;
                uint2 pr;
                pr.x = cvtpk(v0, v1);
                pr.y = cvtpk(v2, v3);
                *reinterpret_cast<uint2*>(&Os[((size_t)qsub * 32 + l31) * 72 + d0]) = pr;
            }
    }
    __syncthreads();

    // coalesced write-out: 64 tokens x 64 d
    const int b = bh / 12, h = bh % 12;
#pragma unroll
    for (int it2 = 0; it2 < 2; ++it2) {
        int idx = tid + it2 * 256;       // 0..511
        int token = idx >> 3;            // 0..63
        int chunk = idx & 7;
        int4 v = *reinterpret_cast<const int4*>(&Os[((size_t)(token >> 5) * 32 + (token & 31)) * 72 + chunk * 8]);
        *reinterpret_cast<int4*>(&attn_out[((size_t)(b * 1024 + qt * 64 + token)) * 768 + h * 64 + chunk * 8]) = v;
    }
}

// ---------------------------------------------------------------------------
// GEMM2: out = attn_bf16 @ w_out (via woutT) + b_out.
// ---------------------------------------------------------------------------
__global__ __launch_bounds__(256) void gemm_out(const u16* __restrict__ A,
                                                const u16* __restrict__ BT,
                                                const float* __restrict__ bias,
                                                float* __restrict__ out) {
    __shared__ u16 As[128][40];
    __shared__ u16 Bs[128][40];
    const int tid = threadIdx.x;
    const int lane = tid & 63;
    const int w = tid >> 6;
    const int wm = w >> 1, wn = w & 1;
    const int lr = lane & 15;
    const int lk = lane >> 4;
    const int row0 = blockIdx.y * 128;
    const int col0 = blockIdx.x * 128;

    f32x4 acc[4][4];
#pragma unroll
    for (int mi = 0; mi < 4; ++mi)
#pragma unroll
        for (int nj = 0; nj < 4; ++nj) acc[mi][nj] = (f32x4){0.f, 0.f, 0.f, 0.f};

    for (int k0 = 0; k0 < 768; k0 += 32) {
#pragma unroll
        for (int l = 0; l < 2; ++l) {
            int idx = tid + l * 256;
            int r = idx >> 2;
            int cg = idx & 3;
            *reinterpret_cast<int4*>(&As[r][cg * 8]) =
                *reinterpret_cast<const int4*>(&A[(size_t)(row0 + r) * 768 + k0 + cg * 8]);
            *reinterpret_cast<int4*>(&Bs[r][cg * 8]) =
                *reinterpret_cast<const int4*>(&BT[(size_t)(col0 + r) * 768 + k0 + cg * 8]);
        }
        __syncthreads();
        bf16x8 af[4], bfr[4];
#pragma unroll
        for (int mi = 0; mi < 4; ++mi)
            af[mi] = *reinterpret_cast<const bf16x8*>(&As[wm * 64 + mi * 16 + lr][lk * 8]);
#pragma unroll
        for (int nj = 0; nj < 4; ++nj)
            bfr[nj] = *reinterpret_cast<const bf16x8*>(&Bs[wn * 64 + nj * 16 + lr][lk * 8]);
#pragma unroll
        for (int mi = 0; mi < 4; ++mi)
#pragma unroll
            for (int nj = 0; nj < 4; ++nj)
                acc[mi][nj] = __builtin_amdgcn_mfma_f32_16x16x32_bf16(af[mi], bfr[nj], acc[mi][nj], 0, 0, 0);
        __syncthreads();
    }

#pragma unroll
    for (int mi = 0; mi < 4; ++mi)
#pragma unroll
        for (int i = 0; i < 4; ++i) {
            int r = row0 + wm * 64 + mi * 16 + lk * 4 + i;
#pragma unroll
            for (int nj = 0; nj < 4; ++nj) {
                int c = col0 + wn * 64 + nj * 16 + lr;
                out[(size_t)r * 768 + c] = acc[mi][nj][i] + bias[c];
            }
        }
}

// ---------------------------------------------------------------------------
extern "C" void kernel_launch(void* const* d_in, const int* in_sizes, int n_in,
                              void* d_out, int out_size, void* d_ws, size_t ws_size,
                              hipStream_t stream) {
    const float* x     = (const float*)d_in[0];
    const float* w_qkv = (const float*)d_in[1];
    const float* w_out = (const float*)d_in[2];
    const float* b_out = (const float*)d_in[3];
    float* out = (float*)d_out;

    u16* ws = (u16*)d_ws;
    const size_t n_x = (size_t)4096 * 768;
    u16* xb     = ws;
    u16* wqkvT  = xb + n_x;
    u16* woutT  = wqkvT + (size_t)2304 * 768;
    u16* Qb     = woutT + (size_t)768 * 768;
    u16* Kb     = Qb + n_x;
    u16* Vtr    = Kb + n_x;                       // [48][64][1024]
    u16* attnb  = Vtr + n_x;

    convert_x<<<(786432 + 255) / 256, 256, 0, stream>>>(x, xb, 786432);
    transpose_convert<<<dim3(72, 24), 256, 0, stream>>>(w_qkv, wqkvT, 768, 2304);
    transpose_convert<<<dim3(24, 24), 256, 0, stream>>>(w_out, woutT, 768, 768);
    gemm_qkv<<<dim3(18, 32), 256, 0, stream>>>(xb, wqkvT, Qb, Kb, Vtr);
    attn_mfma<<<768, 256, 0, stream>>>(Qb, Kb, Vtr, attnb);
    gemm_out<<<dim3(6, 32), 256, 0, stream>>>(attnb, woutT, b_out, out);
}

// Round 6
// 99.256 us; speedup vs baseline: 1.4386x; 1.4386x over previous
//
#include <hip/hip_runtime.h>
#include <math.h>

// x:      [4,1024,768] fp32 -> bf16
// w_qkv:  [768,2304]   fp32 -> bf16 transposed [2304,768]
// w_out:  [768,768]    fp32 -> bf16 transposed [768,768]
// b_out:  [768]        fp32
// out:    [4,1024,768] fp32
// HEADS=12, DH=64.  Q pre-scaled by 0.125*log2(e) -> softmax in exp2 domain.
//
// Q/K/V are stored in MFMA-FRAGMENT-ORDER global layouts so the attention
// kernel's fragment loads are base + lane*16B (fully coalesced, no LDS):
//   Qf,Kf: [bh][blk32][kt(4)][hi(2)][r(32)][j(8)]   (elem (n,d): blk=n>>5, kt=d>>4, hi=(d>>3)&1, r=n&31, j=d&7)
//   Vf:    [bh][blk64][ks(4)][hi(2)][d(64)][j(8)]   (elem (n,d): blk=n>>6, ks=(n>>4)&3, hi=(n>>3)&1, j=n&7)

typedef __attribute__((ext_vector_type(8))) __bf16 bf16x8;
typedef __attribute__((ext_vector_type(4))) float f32x4;
typedef __attribute__((ext_vector_type(16))) float f32x16;
typedef unsigned short u16;
typedef unsigned int u32;

#define ZERO16 {0,0,0,0,0,0,0,0,0,0,0,0,0,0,0,0}

__device__ __forceinline__ u16 f2bf(float f) {
    union { float f; unsigned u; } v; v.f = f;
    unsigned r = v.u + 0x7FFF + ((v.u >> 16) & 1);   // RNE
    return (u16)(r >> 16);
}

__device__ __forceinline__ u32 cvtpk(float lo, float hi) {
    u32 r;
    asm("v_cvt_pk_bf16_f32 %0, %1, %2" : "=v"(r) : "v"(lo), "v"(hi));
    return r;
}
// cross-half (lane ^ 32) exchange via shfl (defined semantics, no alias hazard)
__device__ __forceinline__ float xhalf_max(float x) {
    float o = __shfl_xor(x, 32);
    return fmaxf(x, o);
}
__device__ __forceinline__ float xhalf_sum(float x) {
    float o = __shfl_xor(x, 32);
    return x + o;
}

// ---------------------------------------------------------------------------
__global__ void convert_x(const float* __restrict__ in, u16* __restrict__ out, int n4) {
    int i = blockIdx.x * blockDim.x + threadIdx.x;
    if (i < n4) {
        float4 v = reinterpret_cast<const float4*>(in)[i];
        union { u16 s[4]; int2 p; } o;
        o.s[0] = f2bf(v.x); o.s[1] = f2bf(v.y); o.s[2] = f2bf(v.z); o.s[3] = f2bf(v.w);
        reinterpret_cast<int2*>(out)[i] = o.p;
    }
}

__global__ __launch_bounds__(256) void transpose_convert(const float* __restrict__ in,
                                                         u16* __restrict__ out,
                                                         int R, int C) {
    __shared__ float T[32][33];
    const int tx = threadIdx.x & 31;
    const int ty = threadIdx.x >> 5;
    const int c0 = blockIdx.x * 32;
    const int r0 = blockIdx.y * 32;
#pragma unroll
    for (int p = 0; p < 4; ++p) {
        int ry = ty + p * 8;
        T[ry][tx] = in[(size_t)(r0 + ry) * C + c0 + tx];
    }
    __syncthreads();
#pragma unroll
    for (int p = 0; p < 4; ++p) {
        int cy = ty + p * 8;
        out[(size_t)(c0 + cy) * R + r0 + tx] = f2bf(T[tx][cy]);
    }
}

// ---------------------------------------------------------------------------
// GEMM1: qkv = x_bf16 @ w_qkv (via wqkvT); scatter into fragment-order
// Qf (scaled), Kf, Vf.
// ---------------------------------------------------------------------------
__global__ __launch_bounds__(256) void gemm_qkv(const u16* __restrict__ A,
                                                const u16* __restrict__ BT,
                                                u16* __restrict__ Qf,
                                                u16* __restrict__ Kf,
                                                u16* __restrict__ Vf) {
    __shared__ u16 As[128][40];
    __shared__ u16 Bs[128][40];
    const int tid = threadIdx.x;
    const int lane = tid & 63;
    const int w = tid >> 6;
    const int wm = w >> 1, wn = w & 1;
    const int lr = lane & 15;
    const int lk = lane >> 4;
    const int row0 = blockIdx.y * 128;
    const int col0 = blockIdx.x * 128;

    f32x4 acc[4][4];
#pragma unroll
    for (int mi = 0; mi < 4; ++mi)
#pragma unroll
        for (int nj = 0; nj < 4; ++nj) acc[mi][nj] = (f32x4){0.f, 0.f, 0.f, 0.f};

    for (int k0 = 0; k0 < 768; k0 += 32) {
#pragma unroll
        for (int l = 0; l < 2; ++l) {
            int idx = tid + l * 256;
            int r = idx >> 2;
            int cg = idx & 3;
            *reinterpret_cast<int4*>(&As[r][cg * 8]) =
                *reinterpret_cast<const int4*>(&A[(size_t)(row0 + r) * 768 + k0 + cg * 8]);
            *reinterpret_cast<int4*>(&Bs[r][cg * 8]) =
                *reinterpret_cast<const int4*>(&BT[(size_t)(col0 + r) * 768 + k0 + cg * 8]);
        }
        __syncthreads();
        bf16x8 af[4], bfr[4];
#pragma unroll
        for (int mi = 0; mi < 4; ++mi)
            af[mi] = *reinterpret_cast<const bf16x8*>(&As[wm * 64 + mi * 16 + lr][lk * 8]);
#pragma unroll
        for (int nj = 0; nj < 4; ++nj)
            bfr[nj] = *reinterpret_cast<const bf16x8*>(&Bs[wn * 64 + nj * 16 + lr][lk * 8]);
#pragma unroll
        for (int mi = 0; mi < 4; ++mi)
#pragma unroll
            for (int nj = 0; nj < 4; ++nj)
                acc[mi][nj] = __builtin_amdgcn_mfma_f32_16x16x32_bf16(af[mi], bfr[nj], acc[mi][nj], 0, 0, 0);
        __syncthreads();
    }

    const int which = col0 / 768;
    const int cb = col0 - which * 768;
#pragma unroll
    for (int mi = 0; mi < 4; ++mi) {
#pragma unroll
        for (int i = 0; i < 4; ++i) {
            int r = row0 + wm * 64 + mi * 16 + lk * 4 + i;
            int b = r >> 10, n = r & 1023;
#pragma unroll
            for (int nj = 0; nj < 4; ++nj) {
                int cw = cb + wn * 64 + nj * 16 + lr;
                int h = cw >> 6, d = cw & 63;
                int bh = b * 12 + h;
                float val = acc[mi][nj][i];
                if (which == 2) {
                    // Vf[bh][n>>6][(n>>4)&3][(n>>3)&1][d][n&7]
                    size_t off = ((((size_t)bh * 16 + (n >> 6)) * 4 + ((n >> 4) & 3)) * 2 + ((n >> 3) & 1)) * 512
                                 + d * 8 + (n & 7);
                    Vf[off] = f2bf(val);
                } else {
                    // Qf/Kf[bh][n>>5][d>>4][(d>>3)&1][n&31][d&7]
                    size_t off = ((((size_t)bh * 32 + (n >> 5)) * 4 + (d >> 4)) * 2 + ((d >> 3) & 1)) * 256
                                 + (n & 31) * 8 + (d & 7);
                    if (which == 0) Qf[off] = f2bf(val * 0.18033688f);   // 0.125*log2(e)
                    else            Kf[off] = f2bf(val);
                }
            }
        }
    }
}

// ---------------------------------------------------------------------------
// Flash attention, swapped-operand 32x32x16 MFMA, fragment-order global
// layouts -> every load is base + lane*16B.  No LDS / barriers in KV loop.
// Block = 4 waves: wave w -> qsub = w&1 (32 q-rows), half = w>>1 (KV parity).
// ---------------------------------------------------------------------------
#define GETO(dt, r) ((dt) == 0 ? o0[r] : o1[r])

__global__ __launch_bounds__(256) void attn_mfma(const u16* __restrict__ Qf,
                                                 const u16* __restrict__ Kf,
                                                 const u16* __restrict__ Vf,
                                                 u16* __restrict__ attn_out) {
    __shared__ float OtM[2][64][33];   // [qsub][d][q] partner O^T
    __shared__ float Lm[2][32], Ll[2][32];
    __shared__ u16 Os[2][32][72];      // [qsub][q][d] merged bf16

    const int tid = threadIdx.x;
    const int lane = tid & 63;
    const int w = tid >> 6;
    const int qsub = w & 1;
    const int half = w >> 1;
    const int l31 = lane & 31;
    const int hi = lane >> 5;

    // XCD swizzle: 96 consecutive remapped ids per XCD -> 6 bh per XCD L2
    const int bid = blockIdx.x;
    const int lin = (bid & 7) * 96 + (bid >> 3);
    const int qt = lin & 15;
    const int bh = lin >> 4;

    const u16* Qh = Qf + (size_t)bh * 65536;
    const u16* Kh = Kf + (size_t)bh * 65536;
    const u16* Vh = Vf + (size_t)bh * 65536;

    // Q fragments (B-operand): Qf[bh][qt*2+qsub][kt][hi][l31][0..7]
    bf16x8 qf[4];
#pragma unroll
    for (int kt = 0; kt < 4; ++kt)
        qf[kt] = *reinterpret_cast<const bf16x8*>(
            Qh + (((size_t)(qt * 2 + qsub) * 4 + kt) * 2 + hi) * 256 + l31 * 8);

    f32x16 o0 = ZERO16, o1 = ZERO16;   // O^T: rows d, col q=l31
    float m = -1e30f, l = 0.f;

    for (int it = 0; it < 8; ++it) {
        const int kb0 = it * 4 + half * 2;    // 32-key block index (kv>>5)
        const int kvb = it * 2 + half;        // 64-key block index (kv>>6)

        // K fragments (A-operand): Kf[bh][kb][kt][hi][l31][0..7]
        bf16x8 kf0[4], kf1[4];
#pragma unroll
        for (int kt = 0; kt < 4; ++kt) {
            kf0[kt] = *reinterpret_cast<const bf16x8*>(
                Kh + (((size_t)kb0 * 4 + kt) * 2 + hi) * 256 + l31 * 8);
            kf1[kt] = *reinterpret_cast<const bf16x8*>(
                Kh + (((size_t)(kb0 + 1) * 4 + kt) * 2 + hi) * 256 + l31 * 8);
        }
        // V fragments (A-operand of PV): Vf[bh][kvb][ks][hi][d][0..7]
        bf16x8 vf0[4], vf1[4];
#pragma unroll
        for (int ks = 0; ks < 4; ++ks) {
            const u16* vb = Vh + (((size_t)kvb * 4 + ks) * 2 + hi) * 512;
            vf0[ks] = *reinterpret_cast<const bf16x8*>(vb + l31 * 8);
            vf1[ks] = *reinterpret_cast<const bf16x8*>(vb + (l31 + 32) * 8);
        }

        // S^T = K Q (pre-scaled, exp2 domain)
        f32x16 s0 = ZERO16, s1 = ZERO16;
        __builtin_amdgcn_s_setprio(1);
#pragma unroll
        for (int kt = 0; kt < 4; ++kt) s0 = __builtin_amdgcn_mfma_f32_32x32x16_bf16(kf0[kt], qf[kt], s0, 0, 0, 0);
#pragma unroll
        for (int kt = 0; kt < 4; ++kt) s1 = __builtin_amdgcn_mfma_f32_32x32x16_bf16(kf1[kt], qf[kt], s1, 0, 0, 0);
        __builtin_amdgcn_s_setprio(0);

        // tile max (in-lane tree + one cross-half exchange)
        float mx[8];
#pragma unroll
        for (int i = 0; i < 8; ++i)
            mx[i] = fmaxf(fmaxf(s0[2*i], s0[2*i+1]), fmaxf(s1[2*i], s1[2*i+1]));
        float pmax = fmaxf(fmaxf(fmaxf(mx[0], mx[1]), fmaxf(mx[2], mx[3])),
                           fmaxf(fmaxf(mx[4], mx[5]), fmaxf(mx[6], mx[7])));
        pmax = xhalf_max(pmax);

        // defer-max rescale (T13, THR=8 in log2 units)
        if (!__all(pmax <= m + 8.f)) {
            float mn = fmaxf(m, pmax);
            float c = __builtin_amdgcn_exp2f(m - mn);
            m = mn; l *= c;
            o0 = o0 * c; o1 = o1 * c;
        }

        // P = exp2(S - m)
#pragma unroll
        for (int r = 0; r < 16; ++r) s0[r] = __builtin_amdgcn_exp2f(s0[r] - m);
#pragma unroll
        for (int r = 0; r < 16; ++r) s1[r] = __builtin_amdgcn_exp2f(s1[r] - m);
        float sm[8];
#pragma unroll
        for (int i = 0; i < 8; ++i)
            sm[i] = (s0[2*i] + s0[2*i+1]) + (s1[2*i] + s1[2*i+1]);
        float tsum = ((sm[0]+sm[1]) + (sm[2]+sm[3])) + ((sm[4]+sm[5]) + (sm[6]+sm[7]));
        l += xhalf_sum(tsum);

        // pack P -> bf16 B-fragments (cross-half exchange via shfl_xor(32))
        bf16x8 pb[4];
#define PACK_GROUP(S, G, OUT)                                           \
        {                                                               \
            u32 X0 = cvtpk(S[8*(G)+0], S[8*(G)+1]);                     \
            u32 X1 = cvtpk(S[8*(G)+2], S[8*(G)+3]);                     \
            u32 Y0 = cvtpk(S[8*(G)+4], S[8*(G)+5]);                     \
            u32 Y1 = cvtpk(S[8*(G)+6], S[8*(G)+7]);                     \
            u32 X0s = (u32)__shfl_xor((int)X0, 32);                     \
            u32 X1s = (u32)__shfl_xor((int)X1, 32);                     \
            u32 Y0s = (u32)__shfl_xor((int)Y0, 32);                     \
            u32 Y1s = (u32)__shfl_xor((int)Y1, 32);                     \
            union { u32 u[4]; bf16x8 v; } pk_;                          \
            pk_.u[0] = hi ? Y0s : X0;                                   \
            pk_.u[1] = hi ? Y1s : X1;                                   \
            pk_.u[2] = hi ? Y0 : X0s;                                   \
            pk_.u[3] = hi ? Y1 : X1s;                                   \
            OUT = pk_.v;                                                \
        }
        PACK_GROUP(s0, 0, pb[0]);
        PACK_GROUP(s0, 1, pb[1]);
        PACK_GROUP(s1, 0, pb[2]);
        PACK_GROUP(s1, 1, pb[3]);
#undef PACK_GROUP

        // O^T += V^T P
        __builtin_amdgcn_s_setprio(1);
#pragma unroll
        for (int ks = 0; ks < 4; ++ks) {
            o0 = __builtin_amdgcn_mfma_f32_32x32x16_bf16(vf0[ks], pb[ks], o0, 0, 0, 0);
            o1 = __builtin_amdgcn_mfma_f32_32x32x16_bf16(vf1[ks], pb[ks], o1, 0, 0, 0);
        }
        __builtin_amdgcn_s_setprio(0);
    }

    // merge the two KV-parity halves via LDS
    if (half == 1) {
#pragma unroll
        for (int dt = 0; dt < 2; ++dt)
#pragma unroll
            for (int r = 0; r < 16; ++r)
                OtM[qsub][dt * 32 + (r & 3) + 8 * (r >> 2) + 4 * hi][l31] = GETO(dt, r);
        Lm[qsub][l31] = m;
        Ll[qsub][l31] = l;
    }
    __syncthreads();
    if (half == 0) {
        float m2 = Lm[qsub][l31], l2 = Ll[qsub][l31];
        float mn = fmaxf(m, m2);
        float a = __builtin_amdgcn_exp2f(m - mn);
        float bsc = __builtin_amdgcn_exp2f(m2 - mn);
        float lm = l * a + l2 * bsc;
        float inv = 1.0f / lm;
        float av = a * inv, bv = bsc * inv;
#pragma unroll
        for (int dt = 0; dt < 2; ++dt)
#pragma unroll
            for (int rq = 0; rq < 4; ++rq) {
                int d0 = dt * 32 + 8 * rq + 4 * hi;
                float v0 = GETO(dt, rq * 4 + 0) * av + OtM[qsub][d0 + 0][l31] * bv;
                float v1 = GETO(dt, rq * 4 + 1) * av + OtM[qsub][d0 + 1][l31] * bv;
                float v2 = GETO(dt, rq * 4 + 2) * av + OtM[qsub][d0 + 2][l31] * bv;
                float v3 = GETO(dt, rq * 4 + 3) * av + OtM[qsub][d0 + 3][l31] * bv;
                uint2 pr;
                pr.x = cvtpk(v0, v1);
                pr.y = cvtpk(v2, v3);
                *reinterpret_cast<uint2*>(&Os[qsub][l31][d0]) = pr;
            }
    }
    __syncthreads();

    // coalesced write-out: 64 tokens x 64 d
    const int b = bh / 12, h = bh % 12;
#pragma unroll
    for (int it2 = 0; it2 < 2; ++it2) {
        int idx = tid + it2 * 256;       // 0..511
        int token = idx >> 3;            // 0..63
        int chunk = idx & 7;
        int4 v = *reinterpret_cast<const int4*>(&Os[token >> 5][token & 31][chunk * 8]);
        *reinterpret_cast<int4*>(&attn_out[((size_t)(b * 1024 + qt * 64 + token)) * 768 + h * 64 + chunk * 8]) = v;
    }
}

// ---------------------------------------------------------------------------
// GEMM2: out = attn_bf16 @ w_out (via woutT) + b_out.
// ---------------------------------------------------------------------------
__global__ __launch_bounds__(256) void gemm_out(const u16* __restrict__ A,
                                                const u16* __restrict__ BT,
                                                const float* __restrict__ bias,
                                                float* __restrict__ out) {
    __shared__ u16 As[128][40];
    __shared__ u16 Bs[128][40];
    const int tid = threadIdx.x;
    const int lane = tid & 63;
    const int w = tid >> 6;
    const int wm = w >> 1, wn = w & 1;
    const int lr = lane & 15;
    const int lk = lane >> 4;
    const int row0 = blockIdx.y * 128;
    const int col0 = blockIdx.x * 128;

    f32x4 acc[4][4];
#pragma unroll
    for (int mi = 0; mi < 4; ++mi)
#pragma unroll
        for (int nj = 0; nj < 4; ++nj) acc[mi][nj] = (f32x4){0.f, 0.f, 0.f, 0.f};

    for (int k0 = 0; k0 < 768; k0 += 32) {
#pragma unroll
        for (int l = 0; l < 2; ++l) {
            int idx = tid + l * 256;
            int r = idx >> 2;
            int cg = idx & 3;
            *reinterpret_cast<int4*>(&As[r][cg * 8]) =
                *reinterpret_cast<const int4*>(&A[(size_t)(row0 + r) * 768 + k0 + cg * 8]);
            *reinterpret_cast<int4*>(&Bs[r][cg * 8]) =
                *reinterpret_cast<const int4*>(&BT[(size_t)(col0 + r) * 768 + k0 + cg * 8]);
        }
        __syncthreads();
        bf16x8 af[4], bfr[4];
#pragma unroll
        for (int mi = 0; mi < 4; ++mi)
            af[mi] = *reinterpret_cast<const bf16x8*>(&As[wm * 64 + mi * 16 + lr][lk * 8]);
#pragma unroll
        for (int nj = 0; nj < 4; ++nj)
            bfr[nj] = *reinterpret_cast<const bf16x8*>(&Bs[wn * 64 + nj * 16 + lr][lk * 8]);
#pragma unroll
        for (int mi = 0; mi < 4; ++mi)
#pragma unroll
            for (int nj = 0; nj < 4; ++nj)
                acc[mi][nj] = __builtin_amdgcn_mfma_f32_16x16x32_bf16(af[mi], bfr[nj], acc[mi][nj], 0, 0, 0);
        __syncthreads();
    }

#pragma unroll
    for (int mi = 0; mi < 4; ++mi)
#pragma unroll
        for (int i = 0; i < 4; ++i) {
            int r = row0 + wm * 64 + mi * 16 + lk * 4 + i;
#pragma unroll
            for (int nj = 0; nj < 4; ++nj) {
                int c = col0 + wn * 64 + nj * 16 + lr;
                out[(size_t)r * 768 + c] = acc[mi][nj][i] + bias[c];
            }
        }
}

// ---------------------------------------------------------------------------
extern "C" void kernel_launch(void* const* d_in, const int* in_sizes, int n_in,
                              void* d_out, int out_size, void* d_ws, size_t ws_size,
                              hipStream_t stream) {
    const float* x     = (const float*)d_in[0];
    const float* w_qkv = (const float*)d_in[1];
    const float* w_out = (const float*)d_in[2];
    const float* b_out = (const float*)d_in[3];
    float* out = (float*)d_out;

    u16* ws = (u16*)d_ws;
    const size_t n_x = (size_t)4096 * 768;
    u16* xb     = ws;
    u16* wqkvT  = xb + n_x;
    u16* woutT  = wqkvT + (size_t)2304 * 768;
    u16* Qfr    = woutT + (size_t)768 * 768;      // fragment-order, 65536/bh
    u16* Kfr    = Qfr + n_x;
    u16* Vfr    = Kfr + n_x;
    u16* attnb  = Vfr + n_x;

    convert_x<<<(786432 + 255) / 256, 256, 0, stream>>>(x, xb, 786432);
    transpose_convert<<<dim3(72, 24), 256, 0, stream>>>(w_qkv, wqkvT, 768, 2304);
    transpose_convert<<<dim3(24, 24), 256, 0, stream>>>(w_out, woutT, 768, 768);
    gemm_qkv<<<dim3(18, 32), 256, 0, stream>>>(xb, wqkvT, Qfr, Kfr, Vfr);
    attn_mfma<<<768, 256, 0, stream>>>(Qfr, Kfr, Vfr, attnb);
    gemm_out<<<dim3(6, 32), 256, 0, stream>>>(attnb, woutT, b_out, out);
}

// Round 7
// 99.113 us; speedup vs baseline: 1.4407x; 1.0014x over previous
//
#include <hip/hip_runtime.h>
#include <math.h>

// x:      [4,1024,768] fp32 -> bf16
// w_qkv:  [768,2304]   fp32 -> bf16 transposed [2304,768]
// w_out:  [768,768]    fp32 -> bf16 transposed [768,768]
// b_out:  [768]        fp32
// out:    [4,1024,768] fp32
// HEADS=12, DH=64.  Q pre-scaled by 0.125*log2(e) -> softmax in exp2 domain.
//
// Q/K/V are stored in MFMA-FRAGMENT-ORDER global layouts so the attention
// kernel's fragment loads are base + lane*16B (fully coalesced, no LDS):
//   Qf,Kf: [bh][blk32][kt(4)][hi(2)][r(32)][j(8)]
//   Vf:    [bh][blk64][ks(4)][hi(2)][d(64)][j(8)]
//
// GEMMs use the m97 structure: global_load_lds width-16 staging into linear
// LDS [128][32] (2-phase double-buffered, one barrier per K-step).

typedef __attribute__((ext_vector_type(8))) __bf16 bf16x8;
typedef __attribute__((ext_vector_type(4))) float f32x4;
typedef __attribute__((ext_vector_type(16))) float f32x16;
typedef unsigned short u16;
typedef unsigned int u32;

#define ZERO16 {0,0,0,0,0,0,0,0,0,0,0,0,0,0,0,0}

__device__ __forceinline__ u16 f2bf(float f) {
    union { float f; unsigned u; } v; v.f = f;
    unsigned r = v.u + 0x7FFF + ((v.u >> 16) & 1);   // RNE
    return (u16)(r >> 16);
}

__device__ __forceinline__ u32 cvtpk(float lo, float hi) {
    u32 r;
    asm("v_cvt_pk_bf16_f32 %0, %1, %2" : "=v"(r) : "v"(lo), "v"(hi));
    return r;
}
__device__ __forceinline__ float xhalf_max(float x) {
    float o = __shfl_xor(x, 32);
    return fmaxf(x, o);
}
__device__ __forceinline__ float xhalf_sum(float x) {
    float o = __shfl_xor(x, 32);
    return x + o;
}

// global -> LDS direct 16B copy (lane i of the wave lands at ldsbase + i*16)
__device__ __forceinline__ void gload_lds16(const u16* g, u16* lds_base) {
    __builtin_amdgcn_global_load_lds(
        (const __attribute__((address_space(1))) unsigned int*)g,
        (__attribute__((address_space(3))) unsigned int*)lds_base,
        16, 0, 0);
}

// ---------------------------------------------------------------------------
__global__ void convert_x(const float* __restrict__ in, u16* __restrict__ out, int n4) {
    int i = blockIdx.x * blockDim.x + threadIdx.x;
    if (i < n4) {
        float4 v = reinterpret_cast<const float4*>(in)[i];
        union { u16 s[4]; int2 p; } o;
        o.s[0] = f2bf(v.x); o.s[1] = f2bf(v.y); o.s[2] = f2bf(v.z); o.s[3] = f2bf(v.w);
        reinterpret_cast<int2*>(out)[i] = o.p;
    }
}

__global__ __launch_bounds__(256) void transpose_convert(const float* __restrict__ in,
                                                         u16* __restrict__ out,
                                                         int R, int C) {
    __shared__ float T[32][33];
    const int tx = threadIdx.x & 31;
    const int ty = threadIdx.x >> 5;
    const int c0 = blockIdx.x * 32;
    const int r0 = blockIdx.y * 32;
#pragma unroll
    for (int p = 0; p < 4; ++p) {
        int ry = ty + p * 8;
        T[ry][tx] = in[(size_t)(r0 + ry) * C + c0 + tx];
    }
    __syncthreads();
#pragma unroll
    for (int p = 0; p < 4; ++p) {
        int cy = ty + p * 8;
        out[(size_t)(c0 + cy) * R + r0 + tx] = f2bf(T[tx][cy]);
    }
}

// ---------------------------------------------------------------------------
// GEMM1: qkv = x_bf16 @ w_qkv (via wqkvT); scatter into fragment-order
// Qf (scaled), Kf, Vf.  m97-style staging, 2-phase dbuf.
// ---------------------------------------------------------------------------
__global__ __launch_bounds__(256) void gemm_qkv(const u16* __restrict__ A,
                                                const u16* __restrict__ BT,
                                                u16* __restrict__ Qf,
                                                u16* __restrict__ Kf,
                                                u16* __restrict__ Vf) {
    __shared__ u16 As[2][128 * 32];
    __shared__ u16 Bs[2][128 * 32];
    const int tid = threadIdx.x;
    const int lane = tid & 63;
    const int w = tid >> 6;
    const int wm = w >> 1, wn = w & 1;
    const int lr = lane & 15;
    const int lk = lane >> 4;
    const int row0 = blockIdx.y * 128;
    const int col0 = blockIdx.x * 128;
    const int sr = lane >> 2;      // staging: row within 16-row stripe
    const int scg = lane & 3;      // staging: 16B col group

    f32x4 acc[4][4];
#pragma unroll
    for (int mi = 0; mi < 4; ++mi)
#pragma unroll
        for (int nj = 0; nj < 4; ++nj) acc[mi][nj] = (f32x4){0.f, 0.f, 0.f, 0.f};

#define STAGE_QKV(BUF, K0)                                                    \
    {                                                                         \
        _Pragma("unroll")                                                     \
        for (int q = 0; q < 2; ++q) {                                         \
            int roff = (q * 4 + w) * 16;                                      \
            gload_lds16(A  + (size_t)(row0 + roff + sr) * 768 + (K0) + scg * 8, \
                        &As[BUF][roff * 32]);                                 \
            gload_lds16(BT + (size_t)(col0 + roff + sr) * 768 + (K0) + scg * 8, \
                        &Bs[BUF][roff * 32]);                                 \
        }                                                                     \
    }

    STAGE_QKV(0, 0);
    __syncthreads();
    int cur = 0;
    for (int t = 0; t < 24; ++t) {
        if (t < 23) STAGE_QKV(cur ^ 1, (t + 1) * 32);
        bf16x8 af[4], bfr[4];
#pragma unroll
        for (int mi = 0; mi < 4; ++mi)
            af[mi] = *reinterpret_cast<const bf16x8*>(&As[cur][(wm * 64 + mi * 16 + lr) * 32 + lk * 8]);
#pragma unroll
        for (int nj = 0; nj < 4; ++nj)
            bfr[nj] = *reinterpret_cast<const bf16x8*>(&Bs[cur][(wn * 64 + nj * 16 + lr) * 32 + lk * 8]);
#pragma unroll
        for (int mi = 0; mi < 4; ++mi)
#pragma unroll
            for (int nj = 0; nj < 4; ++nj)
                acc[mi][nj] = __builtin_amdgcn_mfma_f32_16x16x32_bf16(af[mi], bfr[nj], acc[mi][nj], 0, 0, 0);
        __syncthreads();
        cur ^= 1;
    }
#undef STAGE_QKV

    const int which = col0 / 768;
    const int cb = col0 - which * 768;
#pragma unroll
    for (int mi = 0; mi < 4; ++mi) {
#pragma unroll
        for (int i = 0; i < 4; ++i) {
            int r = row0 + wm * 64 + mi * 16 + lk * 4 + i;
            int b = r >> 10, n = r & 1023;
#pragma unroll
            for (int nj = 0; nj < 4; ++nj) {
                int cw = cb + wn * 64 + nj * 16 + lr;
                int h = cw >> 6, d = cw & 63;
                int bh = b * 12 + h;
                float val = acc[mi][nj][i];
                if (which == 2) {
                    size_t off = ((((size_t)bh * 16 + (n >> 6)) * 4 + ((n >> 4) & 3)) * 2 + ((n >> 3) & 1)) * 512
                                 + d * 8 + (n & 7);
                    Vf[off] = f2bf(val);
                } else {
                    size_t off = ((((size_t)bh * 32 + (n >> 5)) * 4 + (d >> 4)) * 2 + ((d >> 3) & 1)) * 256
                                 + (n & 31) * 8 + (d & 7);
                    if (which == 0) Qf[off] = f2bf(val * 0.18033688f);   // 0.125*log2(e)
                    else            Kf[off] = f2bf(val);
                }
            }
        }
    }
}

// ---------------------------------------------------------------------------
// Flash attention, swapped-operand 32x32x16 MFMA, fragment-order global
// layouts -> every load is base + lane*16B.  No LDS / barriers in KV loop.
// ---------------------------------------------------------------------------
#define GETO(dt, r) ((dt) == 0 ? o0[r] : o1[r])

__global__ __launch_bounds__(256) void attn_mfma(const u16* __restrict__ Qf,
                                                 const u16* __restrict__ Kf,
                                                 const u16* __restrict__ Vf,
                                                 u16* __restrict__ attn_out) {
    __shared__ float OtM[2][64][33];   // [qsub][d][q] partner O^T
    __shared__ float Lm[2][32], Ll[2][32];
    __shared__ u16 Os[2][32][72];      // [qsub][q][d] merged bf16

    const int tid = threadIdx.x;
    const int lane = tid & 63;
    const int w = tid >> 6;
    const int qsub = w & 1;
    const int half = w >> 1;
    const int l31 = lane & 31;
    const int hi = lane >> 5;

    const int bid = blockIdx.x;
    const int lin = (bid & 7) * 96 + (bid >> 3);
    const int qt = lin & 15;
    const int bh = lin >> 4;

    const u16* Qh = Qf + (size_t)bh * 65536;
    const u16* Kh = Kf + (size_t)bh * 65536;
    const u16* Vh = Vf + (size_t)bh * 65536;

    bf16x8 qf[4];
#pragma unroll
    for (int kt = 0; kt < 4; ++kt)
        qf[kt] = *reinterpret_cast<const bf16x8*>(
            Qh + (((size_t)(qt * 2 + qsub) * 4 + kt) * 2 + hi) * 256 + l31 * 8);

    f32x16 o0 = ZERO16, o1 = ZERO16;
    float m = -1e30f, l = 0.f;

    for (int it = 0; it < 8; ++it) {
        const int kb0 = it * 4 + half * 2;
        const int kvb = it * 2 + half;

        bf16x8 kf0[4], kf1[4];
#pragma unroll
        for (int kt = 0; kt < 4; ++kt) {
            kf0[kt] = *reinterpret_cast<const bf16x8*>(
                Kh + (((size_t)kb0 * 4 + kt) * 2 + hi) * 256 + l31 * 8);
            kf1[kt] = *reinterpret_cast<const bf16x8*>(
                Kh + (((size_t)(kb0 + 1) * 4 + kt) * 2 + hi) * 256 + l31 * 8);
        }
        bf16x8 vf0[4], vf1[4];
#pragma unroll
        for (int ks = 0; ks < 4; ++ks) {
            const u16* vb = Vh + (((size_t)kvb * 4 + ks) * 2 + hi) * 512;
            vf0[ks] = *reinterpret_cast<const bf16x8*>(vb + l31 * 8);
            vf1[ks] = *reinterpret_cast<const bf16x8*>(vb + (l31 + 32) * 8);
        }

        f32x16 s0 = ZERO16, s1 = ZERO16;
        __builtin_amdgcn_s_setprio(1);
#pragma unroll
        for (int kt = 0; kt < 4; ++kt) s0 = __builtin_amdgcn_mfma_f32_32x32x16_bf16(kf0[kt], qf[kt], s0, 0, 0, 0);
#pragma unroll
        for (int kt = 0; kt < 4; ++kt) s1 = __builtin_amdgcn_mfma_f32_32x32x16_bf16(kf1[kt], qf[kt], s1, 0, 0, 0);
        __builtin_amdgcn_s_setprio(0);

        float mx[8];
#pragma unroll
        for (int i = 0; i < 8; ++i)
            mx[i] = fmaxf(fmaxf(s0[2*i], s0[2*i+1]), fmaxf(s1[2*i], s1[2*i+1]));
        float pmax = fmaxf(fmaxf(fmaxf(mx[0], mx[1]), fmaxf(mx[2], mx[3])),
                           fmaxf(fmaxf(mx[4], mx[5]), fmaxf(mx[6], mx[7])));
        pmax = xhalf_max(pmax);

        if (!__all(pmax <= m + 8.f)) {
            float mn = fmaxf(m, pmax);
            float c = __builtin_amdgcn_exp2f(m - mn);
            m = mn; l *= c;
            o0 = o0 * c; o1 = o1 * c;
        }

#pragma unroll
        for (int r = 0; r < 16; ++r) s0[r] = __builtin_amdgcn_exp2f(s0[r] - m);
#pragma unroll
        for (int r = 0; r < 16; ++r) s1[r] = __builtin_amdgcn_exp2f(s1[r] - m);
        float sm[8];
#pragma unroll
        for (int i = 0; i < 8; ++i)
            sm[i] = (s0[2*i] + s0[2*i+1]) + (s1[2*i] + s1[2*i+1]);
        float tsum = ((sm[0]+sm[1]) + (sm[2]+sm[3])) + ((sm[4]+sm[5]) + (sm[6]+sm[7]));
        l += xhalf_sum(tsum);

        bf16x8 pb[4];
#define PACK_GROUP(S, G, OUT)                                           \
        {                                                               \
            u32 X0 = cvtpk(S[8*(G)+0], S[8*(G)+1]);                     \
            u32 X1 = cvtpk(S[8*(G)+2], S[8*(G)+3]);                     \
            u32 Y0 = cvtpk(S[8*(G)+4], S[8*(G)+5]);                     \
            u32 Y1 = cvtpk(S[8*(G)+6], S[8*(G)+7]);                     \
            u32 X0s = (u32)__shfl_xor((int)X0, 32);                     \
            u32 X1s = (u32)__shfl_xor((int)X1, 32);                     \
            u32 Y0s = (u32)__shfl_xor((int)Y0, 32);                     \
            u32 Y1s = (u32)__shfl_xor((int)Y1, 32);                     \
            union { u32 u[4]; bf16x8 v; } pk_;                          \
            pk_.u[0] = hi ? Y0s : X0;                                   \
            pk_.u[1] = hi ? Y1s : X1;                                   \
            pk_.u[2] = hi ? Y0 : X0s;                                   \
            pk_.u[3] = hi ? Y1 : X1s;                                   \
            OUT = pk_.v;                                                \
        }
        PACK_GROUP(s0, 0, pb[0]);
        PACK_GROUP(s0, 1, pb[1]);
        PACK_GROUP(s1, 0, pb[2]);
        PACK_GROUP(s1, 1, pb[3]);
#undef PACK_GROUP

        __builtin_amdgcn_s_setprio(1);
#pragma unroll
        for (int ks = 0; ks < 4; ++ks) {
            o0 = __builtin_amdgcn_mfma_f32_32x32x16_bf16(vf0[ks], pb[ks], o0, 0, 0, 0);
            o1 = __builtin_amdgcn_mfma_f32_32x32x16_bf16(vf1[ks], pb[ks], o1, 0, 0, 0);
        }
        __builtin_amdgcn_s_setprio(0);
    }

    if (half == 1) {
#pragma unroll
        for (int dt = 0; dt < 2; ++dt)
#pragma unroll
            for (int r = 0; r < 16; ++r)
                OtM[qsub][dt * 32 + (r & 3) + 8 * (r >> 2) + 4 * hi][l31] = GETO(dt, r);
        Lm[qsub][l31] = m;
        Ll[qsub][l31] = l;
    }
    __syncthreads();
    if (half == 0) {
        float m2 = Lm[qsub][l31], l2 = Ll[qsub][l31];
        float mn = fmaxf(m, m2);
        float a = __builtin_amdgcn_exp2f(m - mn);
        float bsc = __builtin_amdgcn_exp2f(m2 - mn);
        float lm = l * a + l2 * bsc;
        float inv = 1.0f / lm;
        float av = a * inv, bv = bsc * inv;
#pragma unroll
        for (int dt = 0; dt < 2; ++dt)
#pragma unroll
            for (int rq = 0; rq < 4; ++rq) {
                int d0 = dt * 32 + 8 * rq + 4 * hi;
                float v0 = GETO(dt, rq * 4 + 0) * av + OtM[qsub][d0 + 0][l31] * bv;
                float v1 = GETO(dt, rq * 4 + 1) * av + OtM[qsub][d0 + 1][l31] * bv;
                float v2 = GETO(dt, rq * 4 + 2) * av + OtM[qsub][d0 + 2][l31] * bv;
                float v3 = GETO(dt, rq * 4 + 3) * av + OtM[qsub][d0 + 3][l31] * bv;
                uint2 pr;
                pr.x = cvtpk(v0, v1);
                pr.y = cvtpk(v2, v3);
                *reinterpret_cast<uint2*>(&Os[qsub][l31][d0]) = pr;
            }
    }
    __syncthreads();

    const int b = bh / 12, h = bh % 12;
#pragma unroll
    for (int it2 = 0; it2 < 2; ++it2) {
        int idx = tid + it2 * 256;
        int token = idx >> 3;
        int chunk = idx & 7;
        int4 v = *reinterpret_cast<const int4*>(&Os[token >> 5][token & 31][chunk * 8]);
        *reinterpret_cast<int4*>(&attn_out[((size_t)(b * 1024 + qt * 64 + token)) * 768 + h * 64 + chunk * 8]) = v;
    }
}

// ---------------------------------------------------------------------------
// GEMM2: out = attn_bf16 @ w_out (via woutT) + b_out.  m97-style staging.
// ---------------------------------------------------------------------------
__global__ __launch_bounds__(256) void gemm_out(const u16* __restrict__ A,
                                                const u16* __restrict__ BT,
                                                const float* __restrict__ bias,
                                                float* __restrict__ out) {
    __shared__ u16 As[2][128 * 32];
    __shared__ u16 Bs[2][128 * 32];
    const int tid = threadIdx.x;
    const int lane = tid & 63;
    const int w = tid >> 6;
    const int wm = w >> 1, wn = w & 1;
    const int lr = lane & 15;
    const int lk = lane >> 4;
    const int row0 = blockIdx.y * 128;
    const int col0 = blockIdx.x * 128;
    const int sr = lane >> 2;
    const int scg = lane & 3;

    f32x4 acc[4][4];
#pragma unroll
    for (int mi = 0; mi < 4; ++mi)
#pragma unroll
        for (int nj = 0; nj < 4; ++nj) acc[mi][nj] = (f32x4){0.f, 0.f, 0.f, 0.f};

#define STAGE_OUT(BUF, K0)                                                    \
    {                                                                         \
        _Pragma("unroll")                                                     \
        for (int q = 0; q < 2; ++q) {                                         \
            int roff = (q * 4 + w) * 16;                                      \
            gload_lds16(A  + (size_t)(row0 + roff + sr) * 768 + (K0) + scg * 8, \
                        &As[BUF][roff * 32]);                                 \
            gload_lds16(BT + (size_t)(col0 + roff + sr) * 768 + (K0) + scg * 8, \
                        &Bs[BUF][roff * 32]);                                 \
        }                                                                     \
    }

    STAGE_OUT(0, 0);
    __syncthreads();
    int cur = 0;
    for (int t = 0; t < 24; ++t) {
        if (t < 23) STAGE_OUT(cur ^ 1, (t + 1) * 32);
        bf16x8 af[4], bfr[4];
#pragma unroll
        for (int mi = 0; mi < 4; ++mi)
            af[mi] = *reinterpret_cast<const bf16x8*>(&As[cur][(wm * 64 + mi * 16 + lr) * 32 + lk * 8]);
#pragma unroll
        for (int nj = 0; nj < 4; ++nj)
            bfr[nj] = *reinterpret_cast<const bf16x8*>(&Bs[cur][(wn * 64 + nj * 16 + lr) * 32 + lk * 8]);
#pragma unroll
        for (int mi = 0; mi < 4; ++mi)
#pragma unroll
            for (int nj = 0; nj < 4; ++nj)
                acc[mi][nj] = __builtin_amdgcn_mfma_f32_16x16x32_bf16(af[mi], bfr[nj], acc[mi][nj], 0, 0, 0);
        __syncthreads();
        cur ^= 1;
    }
#undef STAGE_OUT

#pragma unroll
    for (int mi = 0; mi < 4; ++mi)
#pragma unroll
        for (int i = 0; i < 4; ++i) {
            int r = row0 + wm * 64 + mi * 16 + lk * 4 + i;
#pragma unroll
            for (int nj = 0; nj < 4; ++nj) {
                int c = col0 + wn * 64 + nj * 16 + lr;
                out[(size_t)r * 768 + c] = acc[mi][nj][i] + bias[c];
            }
        }
}

// ---------------------------------------------------------------------------
extern "C" void kernel_launch(void* const* d_in, const int* in_sizes, int n_in,
                              void* d_out, int out_size, void* d_ws, size_t ws_size,
                              hipStream_t stream) {
    const float* x     = (const float*)d_in[0];
    const float* w_qkv = (const float*)d_in[1];
    const float* w_out = (const float*)d_in[2];
    const float* b_out = (const float*)d_in[3];
    float* out = (float*)d_out;

    u16* ws = (u16*)d_ws;
    const size_t n_x = (size_t)4096 * 768;
    u16* xb     = ws;
    u16* wqkvT  = xb + n_x;
    u16* woutT  = wqkvT + (size_t)2304 * 768;
    u16* Qfr    = woutT + (size_t)768 * 768;      // fragment-order, 65536/bh
    u16* Kfr    = Qfr + n_x;
    u16* Vfr    = Kfr + n_x;
    u16* attnb  = Vfr + n_x;

    convert_x<<<(786432 + 255) / 256, 256, 0, stream>>>(x, xb, 786432);
    transpose_convert<<<dim3(72, 24), 256, 0, stream>>>(w_qkv, wqkvT, 768, 2304);
    transpose_convert<<<dim3(24, 24), 256, 0, stream>>>(w_out, woutT, 768, 768);
    gemm_qkv<<<dim3(18, 32), 256, 0, stream>>>(xb, wqkvT, Qfr, Kfr, Vfr);
    attn_mfma<<<768, 256, 0, stream>>>(Qfr, Kfr, Vfr, attnb);
    gemm_out<<<dim3(6, 32), 256, 0, stream>>>(attnb, woutT, b_out, out);
}

// Round 8
// 89.766 us; speedup vs baseline: 1.5907x; 1.1041x over previous
//
#include <hip/hip_runtime.h>
#include <math.h>

// x:      [4,1024,768] fp32 -> bf16
// w_qkv:  [768,2304]   fp32 -> bf16 transposed [2304,768]
// w_out:  [768,768]    fp32 -> bf16 transposed [768,768]
// b_out:  [768]        fp32
// out:    [4,1024,768] fp32
// HEADS=12, DH=64.  Q pre-scaled by 0.125*log2(e) -> softmax in exp2 domain.
//
// Q/K/V in MFMA-fragment-order global layouts (attn loads = base + lane*16B):
//   Qf,Kf: [bh][blk32][kt(4)][hi(2)][r(32)][j(8)]
//   Vf:    [bh][blk64][ks(4)][hi(2)][d(64)][j(8)]
//
// GEMMs: 128x128 tile, global_load_lds width-16 staging, 3-buffer depth-2
// pipeline with COUNTED vmcnt (never drains in the main loop) + raw s_barrier.

typedef __attribute__((ext_vector_type(8))) __bf16 bf16x8;
typedef __attribute__((ext_vector_type(4))) float f32x4;
typedef __attribute__((ext_vector_type(16))) float f32x16;
typedef unsigned short u16;
typedef unsigned int u32;

#define ZERO16 {0,0,0,0,0,0,0,0,0,0,0,0,0,0,0,0}

__device__ __forceinline__ u16 f2bf(float f) {
    union { float f; unsigned u; } v; v.f = f;
    unsigned r = v.u + 0x7FFF + ((v.u >> 16) & 1);   // RNE
    return (u16)(r >> 16);
}

__device__ __forceinline__ u32 cvtpk(float lo, float hi) {
    u32 r;
    asm("v_cvt_pk_bf16_f32 %0, %1, %2" : "=v"(r) : "v"(lo), "v"(hi));
    return r;
}
__device__ __forceinline__ float xhalf_max(float x) {
    float o = __shfl_xor(x, 32);
    return fmaxf(x, o);
}
__device__ __forceinline__ float xhalf_sum(float x) {
    float o = __shfl_xor(x, 32);
    return x + o;
}

// global -> LDS direct 16B copy (lane i of the wave lands at ldsbase + i*16)
__device__ __forceinline__ void gload_lds16(const u16* g, u16* lds_base) {
    __builtin_amdgcn_global_load_lds(
        (const __attribute__((address_space(1))) unsigned int*)g,
        (__attribute__((address_space(3))) unsigned int*)lds_base,
        16, 0, 0);
}

// ---------------------------------------------------------------------------
__global__ void convert_x(const float* __restrict__ in, u16* __restrict__ out, int n4) {
    int i = blockIdx.x * blockDim.x + threadIdx.x;
    if (i < n4) {
        float4 v = reinterpret_cast<const float4*>(in)[i];
        union { u16 s[4]; int2 p; } o;
        o.s[0] = f2bf(v.x); o.s[1] = f2bf(v.y); o.s[2] = f2bf(v.z); o.s[3] = f2bf(v.w);
        reinterpret_cast<int2*>(out)[i] = o.p;
    }
}

__global__ __launch_bounds__(256) void transpose_convert(const float* __restrict__ in,
                                                         u16* __restrict__ out,
                                                         int R, int C) {
    __shared__ float T[32][33];
    const int tx = threadIdx.x & 31;
    const int ty = threadIdx.x >> 5;
    const int c0 = blockIdx.x * 32;
    const int r0 = blockIdx.y * 32;
#pragma unroll
    for (int p = 0; p < 4; ++p) {
        int ry = ty + p * 8;
        T[ry][tx] = in[(size_t)(r0 + ry) * C + c0 + tx];
    }
    __syncthreads();
#pragma unroll
    for (int p = 0; p < 4; ++p) {
        int cy = ty + p * 8;
        out[(size_t)(c0 + cy) * R + r0 + tx] = f2bf(T[tx][cy]);
    }
}

// ---------------------------------------------------------------------------
// GEMM1: qkv = x_bf16 @ w_qkv (via wqkvT); scatter into fragment-order
// Qf (scaled), Kf, Vf.  Counted-vmcnt 3-buffer pipeline.
// ---------------------------------------------------------------------------
__global__ __launch_bounds__(256) void gemm_qkv(const u16* __restrict__ A,
                                                const u16* __restrict__ BT,
                                                u16* __restrict__ Qf,
                                                u16* __restrict__ Kf,
                                                u16* __restrict__ Vf) {
    __shared__ u16 As[3][128 * 32];
    __shared__ u16 Bs[3][128 * 32];
    const int tid = threadIdx.x;
    const int lane = tid & 63;
    const int w = tid >> 6;
    const int wm = w >> 1, wn = w & 1;
    const int lr = lane & 15;
    const int lk = lane >> 4;
    // bijective XCD swizzle: 576 = 8 * 72; each XCD gets 4 row-panels x 18 cols
    const int swz = (blockIdx.x & 7) * 72 + (blockIdx.x >> 3);
    const int col0 = (swz % 18) * 128;
    const int row0 = (swz / 18) * 128;
    const int sr = lane >> 2;      // staging row within 16-row stripe
    const int scg = lane & 3;      // staging 16B col group

    f32x4 acc[4][4];
#pragma unroll
    for (int mi = 0; mi < 4; ++mi)
#pragma unroll
        for (int nj = 0; nj < 4; ++nj) acc[mi][nj] = (f32x4){0.f, 0.f, 0.f, 0.f};

#define STAGE(BUF, K0)                                                        \
    {                                                                         \
        _Pragma("unroll")                                                     \
        for (int q = 0; q < 2; ++q) {                                         \
            int roff = (q * 4 + w) * 16;                                      \
            gload_lds16(A  + (size_t)(row0 + roff + sr) * 768 + (K0) + scg * 8, \
                        &As[BUF][roff * 32]);                                 \
            gload_lds16(BT + (size_t)(col0 + roff + sr) * 768 + (K0) + scg * 8, \
                        &Bs[BUF][roff * 32]);                                 \
        }                                                                     \
    }
#define COMPUTE(BUF)                                                          \
    {                                                                         \
        bf16x8 af[4], bfr[4];                                                 \
        _Pragma("unroll")                                                     \
        for (int mi = 0; mi < 4; ++mi)                                        \
            af[mi] = *reinterpret_cast<const bf16x8*>(&As[BUF][(wm * 64 + mi * 16 + lr) * 32 + lk * 8]); \
        _Pragma("unroll")                                                     \
        for (int nj = 0; nj < 4; ++nj)                                        \
            bfr[nj] = *reinterpret_cast<const bf16x8*>(&Bs[BUF][(wn * 64 + nj * 16 + lr) * 32 + lk * 8]); \
        __builtin_amdgcn_s_setprio(1);                                        \
        _Pragma("unroll")                                                     \
        for (int mi = 0; mi < 4; ++mi)                                        \
            _Pragma("unroll")                                                 \
            for (int nj = 0; nj < 4; ++nj)                                    \
                acc[mi][nj] = __builtin_amdgcn_mfma_f32_16x16x32_bf16(af[mi], bfr[nj], acc[mi][nj], 0, 0, 0); \
        __builtin_amdgcn_s_setprio(0);                                        \
    }

    STAGE(0, 0);
    STAGE(1, 32);
    int cur = 0;
    for (int t = 0; t < 22; ++t) {
        asm volatile("s_waitcnt vmcnt(4)" ::: "memory");   // tile t landed; t+1 in flight
        __builtin_amdgcn_s_barrier();
        int nb = cur + 2; if (nb >= 3) nb -= 3;
        STAGE(nb, (t + 2) * 32);
        COMPUTE(cur);
        ++cur; if (cur == 3) cur = 0;
    }
    asm volatile("s_waitcnt vmcnt(4)" ::: "memory");
    __builtin_amdgcn_s_barrier();
    COMPUTE(cur);
    ++cur; if (cur == 3) cur = 0;
    asm volatile("s_waitcnt vmcnt(0)" ::: "memory");
    __builtin_amdgcn_s_barrier();
    COMPUTE(cur);
#undef STAGE
#undef COMPUTE

    const int which = col0 / 768;
    const int cb = col0 - which * 768;
#pragma unroll
    for (int mi = 0; mi < 4; ++mi) {
#pragma unroll
        for (int i = 0; i < 4; ++i) {
            int r = row0 + wm * 64 + mi * 16 + lk * 4 + i;
            int b = r >> 10, n = r & 1023;
#pragma unroll
            for (int nj = 0; nj < 4; ++nj) {
                int cw = cb + wn * 64 + nj * 16 + lr;
                int h = cw >> 6, d = cw & 63;
                int bh = b * 12 + h;
                float val = acc[mi][nj][i];
                if (which == 2) {
                    size_t off = ((((size_t)bh * 16 + (n >> 6)) * 4 + ((n >> 4) & 3)) * 2 + ((n >> 3) & 1)) * 512
                                 + d * 8 + (n & 7);
                    Vf[off] = f2bf(val);
                } else {
                    size_t off = ((((size_t)bh * 32 + (n >> 5)) * 4 + (d >> 4)) * 2 + ((d >> 3) & 1)) * 256
                                 + (n & 31) * 8 + (d & 7);
                    if (which == 0) Qf[off] = f2bf(val * 0.18033688f);   // 0.125*log2(e)
                    else            Kf[off] = f2bf(val);
                }
            }
        }
    }
}

// ---------------------------------------------------------------------------
// Flash attention, swapped-operand 32x32x16 MFMA, fragment-order global
// layouts -> every load is base + lane*16B.  No LDS / barriers in KV loop.
// ---------------------------------------------------------------------------
#define GETO(dt, r) ((dt) == 0 ? o0[r] : o1[r])

__global__ __launch_bounds__(256) void attn_mfma(const u16* __restrict__ Qf,
                                                 const u16* __restrict__ Kf,
                                                 const u16* __restrict__ Vf,
                                                 u16* __restrict__ attn_out) {
    __shared__ float OtM[2][64][33];
    __shared__ float Lm[2][32], Ll[2][32];
    __shared__ u16 Os[2][32][72];

    const int tid = threadIdx.x;
    const int lane = tid & 63;
    const int w = tid >> 6;
    const int qsub = w & 1;
    const int half = w >> 1;
    const int l31 = lane & 31;
    const int hi = lane >> 5;

    const int bid = blockIdx.x;
    const int lin = (bid & 7) * 96 + (bid >> 3);
    const int qt = lin & 15;
    const int bh = lin >> 4;

    const u16* Qh = Qf + (size_t)bh * 65536;
    const u16* Kh = Kf + (size_t)bh * 65536;
    const u16* Vh = Vf + (size_t)bh * 65536;

    bf16x8 qf[4];
#pragma unroll
    for (int kt = 0; kt < 4; ++kt)
        qf[kt] = *reinterpret_cast<const bf16x8*>(
            Qh + (((size_t)(qt * 2 + qsub) * 4 + kt) * 2 + hi) * 256 + l31 * 8);

    f32x16 o0 = ZERO16, o1 = ZERO16;
    float m = -1e30f, l = 0.f;

    for (int it = 0; it < 8; ++it) {
        const int kb0 = it * 4 + half * 2;
        const int kvb = it * 2 + half;

        bf16x8 kf0[4], kf1[4];
#pragma unroll
        for (int kt = 0; kt < 4; ++kt) {
            kf0[kt] = *reinterpret_cast<const bf16x8*>(
                Kh + (((size_t)kb0 * 4 + kt) * 2 + hi) * 256 + l31 * 8);
            kf1[kt] = *reinterpret_cast<const bf16x8*>(
                Kh + (((size_t)(kb0 + 1) * 4 + kt) * 2 + hi) * 256 + l31 * 8);
        }
        bf16x8 vf0[4], vf1[4];
#pragma unroll
        for (int ks = 0; ks < 4; ++ks) {
            const u16* vb = Vh + (((size_t)kvb * 4 + ks) * 2 + hi) * 512;
            vf0[ks] = *reinterpret_cast<const bf16x8*>(vb + l31 * 8);
            vf1[ks] = *reinterpret_cast<const bf16x8*>(vb + (l31 + 32) * 8);
        }

        f32x16 s0 = ZERO16, s1 = ZERO16;
        __builtin_amdgcn_s_setprio(1);
#pragma unroll
        for (int kt = 0; kt < 4; ++kt) s0 = __builtin_amdgcn_mfma_f32_32x32x16_bf16(kf0[kt], qf[kt], s0, 0, 0, 0);
#pragma unroll
        for (int kt = 0; kt < 4; ++kt) s1 = __builtin_amdgcn_mfma_f32_32x32x16_bf16(kf1[kt], qf[kt], s1, 0, 0, 0);
        __builtin_amdgcn_s_setprio(0);

        float mx[8];
#pragma unroll
        for (int i = 0; i < 8; ++i)
            mx[i] = fmaxf(fmaxf(s0[2*i], s0[2*i+1]), fmaxf(s1[2*i], s1[2*i+1]));
        float pmax = fmaxf(fmaxf(fmaxf(mx[0], mx[1]), fmaxf(mx[2], mx[3])),
                           fmaxf(fmaxf(mx[4], mx[5]), fmaxf(mx[6], mx[7])));
        pmax = xhalf_max(pmax);

        if (!__all(pmax <= m + 8.f)) {
            float mn = fmaxf(m, pmax);
            float c = __builtin_amdgcn_exp2f(m - mn);
            m = mn; l *= c;
            o0 = o0 * c; o1 = o1 * c;
        }

#pragma unroll
        for (int r = 0; r < 16; ++r) s0[r] = __builtin_amdgcn_exp2f(s0[r] - m);
#pragma unroll
        for (int r = 0; r < 16; ++r) s1[r] = __builtin_amdgcn_exp2f(s1[r] - m);
        float sm[8];
#pragma unroll
        for (int i = 0; i < 8; ++i)
            sm[i] = (s0[2*i] + s0[2*i+1]) + (s1[2*i] + s1[2*i+1]);
        float tsum = ((sm[0]+sm[1]) + (sm[2]+sm[3])) + ((sm[4]+sm[5]) + (sm[6]+sm[7]));
        l += xhalf_sum(tsum);

        bf16x8 pb[4];
#define PACK_GROUP(S, G, OUT)                                           \
        {                                                               \
            u32 X0 = cvtpk(S[8*(G)+0], S[8*(G)+1]);                     \
            u32 X1 = cvtpk(S[8*(G)+2], S[8*(G)+3]);                     \
            u32 Y0 = cvtpk(S[8*(G)+4], S[8*(G)+5]);                     \
            u32 Y1 = cvtpk(S[8*(G)+6], S[8*(G)+7]);                     \
            u32 X0s = (u32)__shfl_xor((int)X0, 32);                     \
            u32 X1s = (u32)__shfl_xor((int)X1, 32);                     \
            u32 Y0s = (u32)__shfl_xor((int)Y0, 32);                     \
            u32 Y1s = (u32)__shfl_xor((int)Y1, 32);                     \
            union { u32 u[4]; bf16x8 v; } pk_;                          \
            pk_.u[0] = hi ? Y0s : X0;                                   \
            pk_.u[1] = hi ? Y1s : X1;                                   \
            pk_.u[2] = hi ? Y0 : X0s;                                   \
            pk_.u[3] = hi ? Y1 : X1s;                                   \
            OUT = pk_.v;                                                \
        }
        PACK_GROUP(s0, 0, pb[0]);
        PACK_GROUP(s0, 1, pb[1]);
        PACK_GROUP(s1, 0, pb[2]);
        PACK_GROUP(s1, 1, pb[3]);
#undef PACK_GROUP

        __builtin_amdgcn_s_setprio(1);
#pragma unroll
        for (int ks = 0; ks < 4; ++ks) {
            o0 = __builtin_amdgcn_mfma_f32_32x32x16_bf16(vf0[ks], pb[ks], o0, 0, 0, 0);
            o1 = __builtin_amdgcn_mfma_f32_32x32x16_bf16(vf1[ks], pb[ks], o1, 0, 0, 0);
        }
        __builtin_amdgcn_s_setprio(0);
    }

    if (half == 1) {
#pragma unroll
        for (int dt = 0; dt < 2; ++dt)
#pragma unroll
            for (int r = 0; r < 16; ++r)
                OtM[qsub][dt * 32 + (r & 3) + 8 * (r >> 2) + 4 * hi][l31] = GETO(dt, r);
        Lm[qsub][l31] = m;
        Ll[qsub][l31] = l;
    }
    __syncthreads();
    if (half == 0) {
        float m2 = Lm[qsub][l31], l2 = Ll[qsub][l31];
        float mn = fmaxf(m, m2);
        float a = __builtin_amdgcn_exp2f(m - mn);
        float bsc = __builtin_amdgcn_exp2f(m2 - mn);
        float lm = l * a + l2 * bsc;
        float inv = 1.0f / lm;
        float av = a * inv, bv = bsc * inv;
#pragma unroll
        for (int dt = 0; dt < 2; ++dt)
#pragma unroll
            for (int rq = 0; rq < 4; ++rq) {
                int d0 = dt * 32 + 8 * rq + 4 * hi;
                float v0 = GETO(dt, rq * 4 + 0) * av + OtM[qsub][d0 + 0][l31] * bv;
                float v1 = GETO(dt, rq * 4 + 1) * av + OtM[qsub][d0 + 1][l31] * bv;
                float v2 = GETO(dt, rq * 4 + 2) * av + OtM[qsub][d0 + 2][l31] * bv;
                float v3 = GETO(dt, rq * 4 + 3) * av + OtM[qsub][d0 + 3][l31] * bv;
                uint2 pr;
                pr.x = cvtpk(v0, v1);
                pr.y = cvtpk(v2, v3);
                *reinterpret_cast<uint2*>(&Os[qsub][l31][d0]) = pr;
            }
    }
    __syncthreads();

    const int b = bh / 12, h = bh % 12;
#pragma unroll
    for (int it2 = 0; it2 < 2; ++it2) {
        int idx = tid + it2 * 256;
        int token = idx >> 3;
        int chunk = idx & 7;
        int4 v = *reinterpret_cast<const int4*>(&Os[token >> 5][token & 31][chunk * 8]);
        *reinterpret_cast<int4*>(&attn_out[((size_t)(b * 1024 + qt * 64 + token)) * 768 + h * 64 + chunk * 8]) = v;
    }
}

// ---------------------------------------------------------------------------
// GEMM2: out = attn_bf16 @ w_out (via woutT) + b_out.  Counted-vmcnt pipeline.
// ---------------------------------------------------------------------------
__global__ __launch_bounds__(256) void gemm_out(const u16* __restrict__ A,
                                                const u16* __restrict__ BT,
                                                const float* __restrict__ bias,
                                                float* __restrict__ out) {
    __shared__ u16 As[3][128 * 32];
    __shared__ u16 Bs[3][128 * 32];
    const int tid = threadIdx.x;
    const int lane = tid & 63;
    const int w = tid >> 6;
    const int wm = w >> 1, wn = w & 1;
    const int lr = lane & 15;
    const int lk = lane >> 4;
    // bijective XCD swizzle: 192 = 8 * 24; each XCD: 4 row-panels x 6 cols
    const int swz = (blockIdx.x & 7) * 24 + (blockIdx.x >> 3);
    const int col0 = (swz % 6) * 128;
    const int row0 = (swz / 6) * 128;
    const int sr = lane >> 2;
    const int scg = lane & 3;

    f32x4 acc[4][4];
#pragma unroll
    for (int mi = 0; mi < 4; ++mi)
#pragma unroll
        for (int nj = 0; nj < 4; ++nj) acc[mi][nj] = (f32x4){0.f, 0.f, 0.f, 0.f};

#define STAGE(BUF, K0)                                                        \
    {                                                                         \
        _Pragma("unroll")                                                     \
        for (int q = 0; q < 2; ++q) {                                         \
            int roff = (q * 4 + w) * 16;                                      \
            gload_lds16(A  + (size_t)(row0 + roff + sr) * 768 + (K0) + scg * 8, \
                        &As[BUF][roff * 32]);                                 \
            gload_lds16(BT + (size_t)(col0 + roff + sr) * 768 + (K0) + scg * 8, \
                        &Bs[BUF][roff * 32]);                                 \
        }                                                                     \
    }
#define COMPUTE(BUF)                                                          \
    {                                                                         \
        bf16x8 af[4], bfr[4];                                                 \
        _Pragma("unroll")                                                     \
        for (int mi = 0; mi < 4; ++mi)                                        \
            af[mi] = *reinterpret_cast<const bf16x8*>(&As[BUF][(wm * 64 + mi * 16 + lr) * 32 + lk * 8]); \
        _Pragma("unroll")                                                     \
        for (int nj = 0; nj < 4; ++nj)                                        \
            bfr[nj] = *reinterpret_cast<const bf16x8*>(&Bs[BUF][(wn * 64 + nj * 16 + lr) * 32 + lk * 8]); \
        __builtin_amdgcn_s_setprio(1);                                        \
        _Pragma("unroll")                                                     \
        for (int mi = 0; mi < 4; ++mi)                                        \
            _Pragma("unroll")                                                 \
            for (int nj = 0; nj < 4; ++nj)                                    \
                acc[mi][nj] = __builtin_amdgcn_mfma_f32_16x16x32_bf16(af[mi], bfr[nj], acc[mi][nj], 0, 0, 0); \
        __builtin_amdgcn_s_setprio(0);                                        \
    }

    STAGE(0, 0);
    STAGE(1, 32);
    int cur = 0;
    for (int t = 0; t < 22; ++t) {
        asm volatile("s_waitcnt vmcnt(4)" ::: "memory");
        __builtin_amdgcn_s_barrier();
        int nb = cur + 2; if (nb >= 3) nb -= 3;
        STAGE(nb, (t + 2) * 32);
        COMPUTE(cur);
        ++cur; if (cur == 3) cur = 0;
    }
    asm volatile("s_waitcnt vmcnt(4)" ::: "memory");
    __builtin_amdgcn_s_barrier();
    COMPUTE(cur);
    ++cur; if (cur == 3) cur = 0;
    asm volatile("s_waitcnt vmcnt(0)" ::: "memory");
    __builtin_amdgcn_s_barrier();
    COMPUTE(cur);
#undef STAGE
#undef COMPUTE

#pragma unroll
    for (int mi = 0; mi < 4; ++mi)
#pragma unroll
        for (int i = 0; i < 4; ++i) {
            int r = row0 + wm * 64 + mi * 16 + lk * 4 + i;
#pragma unroll
            for (int nj = 0; nj < 4; ++nj) {
                int c = col0 + wn * 64 + nj * 16 + lr;
                out[(size_t)r * 768 + c] = acc[mi][nj][i] + bias[c];
            }
        }
}

// ---------------------------------------------------------------------------
extern "C" void kernel_launch(void* const* d_in, const int* in_sizes, int n_in,
                              void* d_out, int out_size, void* d_ws, size_t ws_size,
                              hipStream_t stream) {
    const float* x     = (const float*)d_in[0];
    const float* w_qkv = (const float*)d_in[1];
    const float* w_out = (const float*)d_in[2];
    const float* b_out = (const float*)d_in[3];
    float* out = (float*)d_out;

    u16* ws = (u16*)d_ws;
    const size_t n_x = (size_t)4096 * 768;
    u16* xb     = ws;
    u16* wqkvT  = xb + n_x;
    u16* woutT  = wqkvT + (size_t)2304 * 768;
    u16* Qfr    = woutT + (size_t)768 * 768;      // fragment-order, 65536/bh
    u16* Kfr    = Qfr + n_x;
    u16* Vfr    = Kfr + n_x;
    u16* attnb  = Vfr + n_x;

    convert_x<<<(786432 + 255) / 256, 256, 0, stream>>>(x, xb, 786432);
    transpose_convert<<<dim3(72, 24), 256, 0, stream>>>(w_qkv, wqkvT, 768, 2304);
    transpose_convert<<<dim3(24, 24), 256, 0, stream>>>(w_out, woutT, 768, 768);
    gemm_qkv<<<576, 256, 0, stream>>>(xb, wqkvT, Qfr, Kfr, Vfr);
    attn_mfma<<<768, 256, 0, stream>>>(Qfr, Kfr, Vfr, attnb);
    gemm_out<<<192, 256, 0, stream>>>(attnb, woutT, b_out, out);
}

// Round 9
// 89.373 us; speedup vs baseline: 1.5977x; 1.0044x over previous
//
#include <hip/hip_runtime.h>
#include <math.h>

// x:      [4,1024,768] fp32 -> bf16
// w_qkv:  [768,2304]   fp32 -> bf16 transposed [2304,768]
// w_out:  [768,768]    fp32 -> bf16 transposed [768,768]
// b_out:  [768]        fp32
// out:    [4,1024,768] fp32
// HEADS=12, DH=64.  Q pre-scaled by 0.125*log2(e) -> softmax in exp2 domain.
//
// Q/K/V in MFMA-fragment-order global layouts (attn loads = base + lane*16B):
//   Qf,Kf: [bh][blk32][kt(4)][hi(2)][r(32)][j(8)]
//   Vf:    [bh][blk64][ks(4)][hi(2)][d(64)][j(8)]
//
// GEMMs: 64x128 tiles (4 waves, wave=32x64), global_load_lds width-16 staging,
// 3-buffer depth-2 counted-vmcnt pipeline (never drains in the main loop).

typedef __attribute__((ext_vector_type(8))) __bf16 bf16x8;
typedef __attribute__((ext_vector_type(4))) float f32x4;
typedef __attribute__((ext_vector_type(16))) float f32x16;
typedef unsigned short u16;
typedef unsigned int u32;

#define ZERO16 {0,0,0,0,0,0,0,0,0,0,0,0,0,0,0,0}

__device__ __forceinline__ u16 f2bf(float f) {
    union { float f; unsigned u; } v; v.f = f;
    unsigned r = v.u + 0x7FFF + ((v.u >> 16) & 1);   // RNE
    return (u16)(r >> 16);
}

__device__ __forceinline__ u32 cvtpk(float lo, float hi) {
    u32 r;
    asm("v_cvt_pk_bf16_f32 %0, %1, %2" : "=v"(r) : "v"(lo), "v"(hi));
    return r;
}
__device__ __forceinline__ float xhalf_max(float x) {
    float o = __shfl_xor(x, 32);
    return fmaxf(x, o);
}
__device__ __forceinline__ float xhalf_sum(float x) {
    float o = __shfl_xor(x, 32);
    return x + o;
}

// global -> LDS direct 16B copy (lane i of the wave lands at ldsbase + i*16)
__device__ __forceinline__ void gload_lds16(const u16* g, u16* lds_base) {
    __builtin_amdgcn_global_load_lds(
        (const __attribute__((address_space(1))) unsigned int*)g,
        (__attribute__((address_space(3))) unsigned int*)lds_base,
        16, 0, 0);
}

// ---------------------------------------------------------------------------
// Fused prep: convert x -> bf16 (blocks 0..3071), transpose+convert w_qkv
// (3072..4799), transpose+convert w_out (4800..5375).
// ---------------------------------------------------------------------------
__global__ __launch_bounds__(256) void prep(const float* __restrict__ x,
                                            const float* __restrict__ w_qkv,
                                            const float* __restrict__ w_out,
                                            u16* __restrict__ xb,
                                            u16* __restrict__ wqkvT,
                                            u16* __restrict__ woutT) {
    __shared__ float T[32][33];
    const int bid = blockIdx.x;
    if (bid < 3072) {
        int i = bid * 256 + threadIdx.x;
        float4 v = reinterpret_cast<const float4*>(x)[i];
        union { u16 s[4]; int2 p; } o;
        o.s[0] = f2bf(v.x); o.s[1] = f2bf(v.y); o.s[2] = f2bf(v.z); o.s[3] = f2bf(v.w);
        reinterpret_cast<int2*>(xb)[i] = o.p;
        return;
    }
    const float* in;
    u16* out;
    int R, C, c0, r0;
    if (bid < 4800) {
        int r = bid - 3072;
        in = w_qkv; out = wqkvT; R = 768; C = 2304;
        c0 = (r % 72) * 32; r0 = (r / 72) * 32;
    } else {
        int r = bid - 4800;
        in = w_out; out = woutT; R = 768; C = 768;
        c0 = (r % 24) * 32; r0 = (r / 24) * 32;
    }
    const int tx = threadIdx.x & 31;
    const int ty = threadIdx.x >> 5;
#pragma unroll
    for (int p = 0; p < 4; ++p) {
        int ry = ty + p * 8;
        T[ry][tx] = in[(size_t)(r0 + ry) * C + c0 + tx];
    }
    __syncthreads();
#pragma unroll
    for (int p = 0; p < 4; ++p) {
        int cy = ty + p * 8;
        out[(size_t)(c0 + cy) * R + r0 + tx] = f2bf(T[tx][cy]);
    }
}

// ---------------------------------------------------------------------------
// GEMM1: qkv = x_bf16 @ w_qkv (via wqkvT); scatter into fragment-order
// Qf (scaled), Kf, Vf.  64x128 tile, counted-vmcnt 3-buffer pipeline.
// ---------------------------------------------------------------------------
__global__ __launch_bounds__(256) void gemm_qkv(const u16* __restrict__ A,
                                                const u16* __restrict__ BT,
                                                u16* __restrict__ Qf,
                                                u16* __restrict__ Kf,
                                                u16* __restrict__ Vf) {
    __shared__ u16 As[3][64 * 32];
    __shared__ u16 Bs[3][128 * 32];
    const int tid = threadIdx.x;
    const int lane = tid & 63;
    const int w = tid >> 6;
    const int wm = w >> 1, wn = w & 1;       // wave = 32x64 of the 64x128 tile
    const int lr = lane & 15;
    const int lk = lane >> 4;
    // bijective XCD swizzle: 1152 = 8 * 144 (M/64=64 panels x N/128=18)
    const int swz = (blockIdx.x & 7) * 144 + (blockIdx.x >> 3);
    const int col0 = (swz % 18) * 128;
    const int row0 = (swz / 18) * 64;
    const int sr = lane >> 2;      // staging row (16 per wave)
    const int scg = lane & 3;      // staging 16B col group

    f32x4 acc[2][4];
#pragma unroll
    for (int mi = 0; mi < 2; ++mi)
#pragma unroll
        for (int nj = 0; nj < 4; ++nj) acc[mi][nj] = (f32x4){0.f, 0.f, 0.f, 0.f};

#define STAGE(BUF, K0)                                                        \
    {                                                                         \
        gload_lds16(A + (size_t)(row0 + w * 16 + sr) * 768 + (K0) + scg * 8,  \
                    &As[BUF][w * 16 * 32]);                                   \
        _Pragma("unroll")                                                     \
        for (int q = 0; q < 2; ++q) {                                         \
            int roff = (q * 4 + w) * 16;                                      \
            gload_lds16(BT + (size_t)(col0 + roff + sr) * 768 + (K0) + scg * 8, \
                        &Bs[BUF][roff * 32]);                                 \
        }                                                                     \
    }
#define COMPUTE(BUF)                                                          \
    {                                                                         \
        bf16x8 af[2], bfr[4];                                                 \
        _Pragma("unroll")                                                     \
        for (int mi = 0; mi < 2; ++mi)                                        \
            af[mi] = *reinterpret_cast<const bf16x8*>(&As[BUF][(wm * 32 + mi * 16 + lr) * 32 + lk * 8]); \
        _Pragma("unroll")                                                     \
        for (int nj = 0; nj < 4; ++nj)                                        \
            bfr[nj] = *reinterpret_cast<const bf16x8*>(&Bs[BUF][(wn * 64 + nj * 16 + lr) * 32 + lk * 8]); \
        __builtin_amdgcn_s_setprio(1);                                        \
        _Pragma("unroll")                                                     \
        for (int mi = 0; mi < 2; ++mi)                                        \
            _Pragma("unroll")                                                 \
            for (int nj = 0; nj < 4; ++nj)                                    \
                acc[mi][nj] = __builtin_amdgcn_mfma_f32_16x16x32_bf16(af[mi], bfr[nj], acc[mi][nj], 0, 0, 0); \
        __builtin_amdgcn_s_setprio(0);                                        \
    }

    STAGE(0, 0);
    STAGE(1, 32);
    int cur = 0;
    for (int t = 0; t < 22; ++t) {
        asm volatile("s_waitcnt vmcnt(3)" ::: "memory");   // tile t landed; t+1 in flight
        __builtin_amdgcn_s_barrier();
        int nb = cur + 2; if (nb >= 3) nb -= 3;
        STAGE(nb, (t + 2) * 32);
        COMPUTE(cur);
        ++cur; if (cur == 3) cur = 0;
    }
    asm volatile("s_waitcnt vmcnt(3)" ::: "memory");
    __builtin_amdgcn_s_barrier();
    COMPUTE(cur);
    ++cur; if (cur == 3) cur = 0;
    asm volatile("s_waitcnt vmcnt(0)" ::: "memory");
    __builtin_amdgcn_s_barrier();
    COMPUTE(cur);
#undef STAGE
#undef COMPUTE

    const int which = col0 / 768;
    const int cb = col0 - which * 768;
#pragma unroll
    for (int mi = 0; mi < 2; ++mi) {
#pragma unroll
        for (int i = 0; i < 4; ++i) {
            int r = row0 + wm * 32 + mi * 16 + lk * 4 + i;
            int b = r >> 10, n = r & 1023;
#pragma unroll
            for (int nj = 0; nj < 4; ++nj) {
                int cw = cb + wn * 64 + nj * 16 + lr;
                int h = cw >> 6, d = cw & 63;
                int bh = b * 12 + h;
                float val = acc[mi][nj][i];
                if (which == 2) {
                    size_t off = ((((size_t)bh * 16 + (n >> 6)) * 4 + ((n >> 4) & 3)) * 2 + ((n >> 3) & 1)) * 512
                                 + d * 8 + (n & 7);
                    Vf[off] = f2bf(val);
                } else {
                    size_t off = ((((size_t)bh * 32 + (n >> 5)) * 4 + (d >> 4)) * 2 + ((d >> 3) & 1)) * 256
                                 + (n & 31) * 8 + (d & 7);
                    if (which == 0) Qf[off] = f2bf(val * 0.18033688f);   // 0.125*log2(e)
                    else            Kf[off] = f2bf(val);
                }
            }
        }
    }
}

// ---------------------------------------------------------------------------
// Flash attention, swapped-operand 32x32x16 MFMA, fragment-order global
// layouts -> every load is base + lane*16B.  No LDS / barriers in KV loop.
// ---------------------------------------------------------------------------
#define GETO(dt, r) ((dt) == 0 ? o0[r] : o1[r])

__global__ __launch_bounds__(256) void attn_mfma(const u16* __restrict__ Qf,
                                                 const u16* __restrict__ Kf,
                                                 const u16* __restrict__ Vf,
                                                 u16* __restrict__ attn_out) {
    __shared__ float OtM[2][64][33];
    __shared__ float Lm[2][32], Ll[2][32];
    __shared__ u16 Os[2][32][72];

    const int tid = threadIdx.x;
    const int lane = tid & 63;
    const int w = tid >> 6;
    const int qsub = w & 1;
    const int half = w >> 1;
    const int l31 = lane & 31;
    const int hi = lane >> 5;

    const int bid = blockIdx.x;
    const int lin = (bid & 7) * 96 + (bid >> 3);
    const int qt = lin & 15;
    const int bh = lin >> 4;

    const u16* Qh = Qf + (size_t)bh * 65536;
    const u16* Kh = Kf + (size_t)bh * 65536;
    const u16* Vh = Vf + (size_t)bh * 65536;

    bf16x8 qf[4];
#pragma unroll
    for (int kt = 0; kt < 4; ++kt)
        qf[kt] = *reinterpret_cast<const bf16x8*>(
            Qh + (((size_t)(qt * 2 + qsub) * 4 + kt) * 2 + hi) * 256 + l31 * 8);

    f32x16 o0 = ZERO16, o1 = ZERO16;
    float m = -1e30f, l = 0.f;

    for (int it = 0; it < 8; ++it) {
        const int kb0 = it * 4 + half * 2;
        const int kvb = it * 2 + half;

        bf16x8 kf0[4], kf1[4];
#pragma unroll
        for (int kt = 0; kt < 4; ++kt) {
            kf0[kt] = *reinterpret_cast<const bf16x8*>(
                Kh + (((size_t)kb0 * 4 + kt) * 2 + hi) * 256 + l31 * 8);
            kf1[kt] = *reinterpret_cast<const bf16x8*>(
                Kh + (((size_t)(kb0 + 1) * 4 + kt) * 2 + hi) * 256 + l31 * 8);
        }
        bf16x8 vf0[4], vf1[4];
#pragma unroll
        for (int ks = 0; ks < 4; ++ks) {
            const u16* vb = Vh + (((size_t)kvb * 4 + ks) * 2 + hi) * 512;
            vf0[ks] = *reinterpret_cast<const bf16x8*>(vb + l31 * 8);
            vf1[ks] = *reinterpret_cast<const bf16x8*>(vb + (l31 + 32) * 8);
        }

        f32x16 s0 = ZERO16, s1 = ZERO16;
        __builtin_amdgcn_s_setprio(1);
#pragma unroll
        for (int kt = 0; kt < 4; ++kt) s0 = __builtin_amdgcn_mfma_f32_32x32x16_bf16(kf0[kt], qf[kt], s0, 0, 0, 0);
#pragma unroll
        for (int kt = 0; kt < 4; ++kt) s1 = __builtin_amdgcn_mfma_f32_32x32x16_bf16(kf1[kt], qf[kt], s1, 0, 0, 0);
        __builtin_amdgcn_s_setprio(0);

        float mx[8];
#pragma unroll
        for (int i = 0; i < 8; ++i)
            mx[i] = fmaxf(fmaxf(s0[2*i], s0[2*i+1]), fmaxf(s1[2*i], s1[2*i+1]));
        float pmax = fmaxf(fmaxf(fmaxf(mx[0], mx[1]), fmaxf(mx[2], mx[3])),
                           fmaxf(fmaxf(mx[4], mx[5]), fmaxf(mx[6], mx[7])));
        pmax = xhalf_max(pmax);

        if (!__all(pmax <= m + 8.f)) {
            float mn = fmaxf(m, pmax);
            float c = __builtin_amdgcn_exp2f(m - mn);
            m = mn; l *= c;
            o0 = o0 * c; o1 = o1 * c;
        }

#pragma unroll
        for (int r = 0; r < 16; ++r) s0[r] = __builtin_amdgcn_exp2f(s0[r] - m);
#pragma unroll
        for (int r = 0; r < 16; ++r) s1[r] = __builtin_amdgcn_exp2f(s1[r] - m);
        float sm[8];
#pragma unroll
        for (int i = 0; i < 8; ++i)
            sm[i] = (s0[2*i] + s0[2*i+1]) + (s1[2*i] + s1[2*i+1]);
        float tsum = ((sm[0]+sm[1]) + (sm[2]+sm[3])) + ((sm[4]+sm[5]) + (sm[6]+sm[7]));
        l += xhalf_sum(tsum);

        bf16x8 pb[4];
#define PACK_GROUP(S, G, OUT)                                           \
        {                                                               \
            u32 X0 = cvtpk(S[8*(G)+0], S[8*(G)+1]);                     \
            u32 X1 = cvtpk(S[8*(G)+2], S[8*(G)+3]);                     \
            u32 Y0 = cvtpk(S[8*(G)+4], S[8*(G)+5]);                     \
            u32 Y1 = cvtpk(S[8*(G)+6], S[8*(G)+7]);                     \
            u32 X0s = (u32)__shfl_xor((int)X0, 32);                     \
            u32 X1s = (u32)__shfl_xor((int)X1, 32);                     \
            u32 Y0s = (u32)__shfl_xor((int)Y0, 32);                     \
            u32 Y1s = (u32)__shfl_xor((int)Y1, 32);                     \
            union { u32 u[4]; bf16x8 v; } pk_;                          \
            pk_.u[0] = hi ? Y0s : X0;                                   \
            pk_.u[1] = hi ? Y1s : X1;                                   \
            pk_.u[2] = hi ? Y0 : X0s;                                   \
            pk_.u[3] = hi ? Y1 : X1s;                                   \
            OUT = pk_.v;                                                \
        }
        PACK_GROUP(s0, 0, pb[0]);
        PACK_GROUP(s0, 1, pb[1]);
        PACK_GROUP(s1, 0, pb[2]);
        PACK_GROUP(s1, 1, pb[3]);
#undef PACK_GROUP

        __builtin_amdgcn_s_setprio(1);
#pragma unroll
        for (int ks = 0; ks < 4; ++ks) {
            o0 = __builtin_amdgcn_mfma_f32_32x32x16_bf16(vf0[ks], pb[ks], o0, 0, 0, 0);
            o1 = __builtin_amdgcn_mfma_f32_32x32x16_bf16(vf1[ks], pb[ks], o1, 0, 0, 0);
        }
        __builtin_amdgcn_s_setprio(0);
    }

    if (half == 1) {
#pragma unroll
        for (int dt = 0; dt < 2; ++dt)
#pragma unroll
            for (int r = 0; r < 16; ++r)
                OtM[qsub][dt * 32 + (r & 3) + 8 * (r >> 2) + 4 * hi][l31] = GETO(dt, r);
        Lm[qsub][l31] = m;
        Ll[qsub][l31] = l;
    }
    __syncthreads();
    if (half == 0) {
        float m2 = Lm[qsub][l31], l2 = Ll[qsub][l31];
        float mn = fmaxf(m, m2);
        float a = __builtin_amdgcn_exp2f(m - mn);
        float bsc = __builtin_amdgcn_exp2f(m2 - mn);
        float lm = l * a + l2 * bsc;
        float inv = 1.0f / lm;
        float av = a * inv, bv = bsc * inv;
#pragma unroll
        for (int dt = 0; dt < 2; ++dt)
#pragma unroll
            for (int rq = 0; rq < 4; ++rq) {
                int d0 = dt * 32 + 8 * rq + 4 * hi;
                float v0 = GETO(dt, rq * 4 + 0) * av + OtM[qsub][d0 + 0][l31] * bv;
                float v1 = GETO(dt, rq * 4 + 1) * av + OtM[qsub][d0 + 1][l31] * bv;
                float v2 = GETO(dt, rq * 4 + 2) * av + OtM[qsub][d0 + 2][l31] * bv;
                float v3 = GETO(dt, rq * 4 + 3) * av + OtM[qsub][d0 + 3][l31] * bv;
                uint2 pr;
                pr.x = cvtpk(v0, v1);
                pr.y = cvtpk(v2, v3);
                *reinterpret_cast<uint2*>(&Os[qsub][l31][d0]) = pr;
            }
    }
    __syncthreads();

    const int b = bh / 12, h = bh % 12;
#pragma unroll
    for (int it2 = 0; it2 < 2; ++it2) {
        int idx = tid + it2 * 256;
        int token = idx >> 3;
        int chunk = idx & 7;
        int4 v = *reinterpret_cast<const int4*>(&Os[token >> 5][token & 31][chunk * 8]);
        *reinterpret_cast<int4*>(&attn_out[((size_t)(b * 1024 + qt * 64 + token)) * 768 + h * 64 + chunk * 8]) = v;
    }
}

// ---------------------------------------------------------------------------
// GEMM2: out = attn_bf16 @ w_out (via woutT) + b_out.  64x128 tile,
// counted-vmcnt pipeline.  384 blocks -> full-machine coverage.
// ---------------------------------------------------------------------------
__global__ __launch_bounds__(256) void gemm_out(const u16* __restrict__ A,
                                                const u16* __restrict__ BT,
                                                const float* __restrict__ bias,
                                                float* __restrict__ out) {
    __shared__ u16 As[3][64 * 32];
    __shared__ u16 Bs[3][128 * 32];
    const int tid = threadIdx.x;
    const int lane = tid & 63;
    const int w = tid >> 6;
    const int wm = w >> 1, wn = w & 1;
    const int lr = lane & 15;
    const int lk = lane >> 4;
    // bijective XCD swizzle: 384 = 8 * 48 (M/64=64 x N/128=6)
    const int swz = (blockIdx.x & 7) * 48 + (blockIdx.x >> 3);
    const int col0 = (swz % 6) * 128;
    const int row0 = (swz / 6) * 64;
    const int sr = lane >> 2;
    const int scg = lane & 3;

    f32x4 acc[2][4];
#pragma unroll
    for (int mi = 0; mi < 2; ++mi)
#pragma unroll
        for (int nj = 0; nj < 4; ++nj) acc[mi][nj] = (f32x4){0.f, 0.f, 0.f, 0.f};

#define STAGE(BUF, K0)                                                        \
    {                                                                         \
        gload_lds16(A + (size_t)(row0 + w * 16 + sr) * 768 + (K0) + scg * 8,  \
                    &As[BUF][w * 16 * 32]);                                   \
        _Pragma("unroll")                                                     \
        for (int q = 0; q < 2; ++q) {                                         \
            int roff = (q * 4 + w) * 16;                                      \
            gload_lds16(BT + (size_t)(col0 + roff + sr) * 768 + (K0) + scg * 8, \
                        &Bs[BUF][roff * 32]);                                 \
        }                                                                     \
    }
#define COMPUTE(BUF)                                                          \
    {                                                                         \
        bf16x8 af[2], bfr[4];                                                 \
        _Pragma("unroll")                                                     \
        for (int mi = 0; mi < 2; ++mi)                                        \
            af[mi] = *reinterpret_cast<const bf16x8*>(&As[BUF][(wm * 32 + mi * 16 + lr) * 32 + lk * 8]); \
        _Pragma("unroll")                                                     \
        for (int nj = 0; nj < 4; ++nj)                                        \
            bfr[nj] = *reinterpret_cast<const bf16x8*>(&Bs[BUF][(wn * 64 + nj * 16 + lr) * 32 + lk * 8]); \
        __builtin_amdgcn_s_setprio(1);                                        \
        _Pragma("unroll")                                                     \
        for (int mi = 0; mi < 2; ++mi)                                        \
            _Pragma("unroll")                                                 \
            for (int nj = 0; nj < 4; ++nj)                                    \
                acc[mi][nj] = __builtin_amdgcn_mfma_f32_16x16x32_bf16(af[mi], bfr[nj], acc[mi][nj], 0, 0, 0); \
        __builtin_amdgcn_s_setprio(0);                                        \
    }

    STAGE(0, 0);
    STAGE(1, 32);
    int cur = 0;
    for (int t = 0; t < 22; ++t) {
        asm volatile("s_waitcnt vmcnt(3)" ::: "memory");
        __builtin_amdgcn_s_barrier();
        int nb = cur + 2; if (nb >= 3) nb -= 3;
        STAGE(nb, (t + 2) * 32);
        COMPUTE(cur);
        ++cur; if (cur == 3) cur = 0;
    }
    asm volatile("s_waitcnt vmcnt(3)" ::: "memory");
    __builtin_amdgcn_s_barrier();
    COMPUTE(cur);
    ++cur; if (cur == 3) cur = 0;
    asm volatile("s_waitcnt vmcnt(0)" ::: "memory");
    __builtin_amdgcn_s_barrier();
    COMPUTE(cur);
#undef STAGE
#undef COMPUTE

#pragma unroll
    for (int mi = 0; mi < 2; ++mi)
#pragma unroll
        for (int i = 0; i < 4; ++i) {
            int r = row0 + wm * 32 + mi * 16 + lk * 4 + i;
#pragma unroll
            for (int nj = 0; nj < 4; ++nj) {
                int c = col0 + wn * 64 + nj * 16 + lr;
                out[(size_t)r * 768 + c] = acc[mi][nj][i] + bias[c];
            }
        }
}

// ---------------------------------------------------------------------------
extern "C" void kernel_launch(void* const* d_in, const int* in_sizes, int n_in,
                              void* d_out, int out_size, void* d_ws, size_t ws_size,
                              hipStream_t stream) {
    const float* x     = (const float*)d_in[0];
    const float* w_qkv = (const float*)d_in[1];
    const float* w_out = (const float*)d_in[2];
    const float* b_out = (const float*)d_in[3];
    float* out = (float*)d_out;

    u16* ws = (u16*)d_ws;
    const size_t n_x = (size_t)4096 * 768;
    u16* xb     = ws;
    u16* wqkvT  = xb + n_x;
    u16* woutT  = wqkvT + (size_t)2304 * 768;
    u16* Qfr    = woutT + (size_t)768 * 768;      // fragment-order, 65536/bh
    u16* Kfr    = Qfr + n_x;
    u16* Vfr    = Kfr + n_x;
    u16* attnb  = Vfr + n_x;

    prep<<<5376, 256, 0, stream>>>(x, w_qkv, w_out, xb, wqkvT, woutT);
    gemm_qkv<<<1152, 256, 0, stream>>>(xb, wqkvT, Qfr, Kfr, Vfr);
    attn_mfma<<<768, 256, 0, stream>>>(Qfr, Kfr, Vfr, attnb);
    gemm_out<<<384, 256, 0, stream>>>(attnb, woutT, b_out, out);
}

// Round 10
// 83.808 us; speedup vs baseline: 1.7038x; 1.0664x over previous
//
#include <hip/hip_runtime.h>
#include <math.h>

// x:      [4,1024,768] fp32 -> bf16
// w_qkv:  [768,2304]   fp32 -> bf16 transposed [2304,768]
// w_out:  [768,768]    fp32 -> bf16 transposed [768,768]
// b_out:  [768]        fp32
// out:    [4,1024,768] fp32
// HEADS=12, DH=64.  Q pre-scaled by 0.125*log2(e) -> softmax in exp2 domain.
//
// Q/K/V in MFMA-fragment-order global layouts (attn loads = base + lane*16B):
//   Qf,Kf: [bh][blk32][kt(4)][hi(2)][r(32)][j(8)]
//   Vf:    [bh][blk64][ks(4)][hi(2)][d(64)][j(8)]
//
// GEMMs: 64x128 tile, REG-STAGED global->reg->LDS pipeline (VGPR loads give
// per-wave MLP; global_load_lds DMA queue was the R7-R9 ~42us ceiling),
// 2 LDS buffers, ONE raw barrier per K-step (no vmcnt-0 drain).

typedef __attribute__((ext_vector_type(8))) __bf16 bf16x8;
typedef __attribute__((ext_vector_type(4))) float f32x4;
typedef __attribute__((ext_vector_type(16))) float f32x16;
typedef unsigned short u16;
typedef unsigned int u32;

#define ZERO16 {0,0,0,0,0,0,0,0,0,0,0,0,0,0,0,0}

__device__ __forceinline__ u16 f2bf(float f) {
    union { float f; unsigned u; } v; v.f = f;
    unsigned r = v.u + 0x7FFF + ((v.u >> 16) & 1);   // RNE
    return (u16)(r >> 16);
}

__device__ __forceinline__ u32 cvtpk(float lo, float hi) {
    u32 r;
    asm("v_cvt_pk_bf16_f32 %0, %1, %2" : "=v"(r) : "v"(lo), "v"(hi));
    return r;
}
__device__ __forceinline__ float xhalf_max(float x) {
    float o = __shfl_xor(x, 32);
    return fmaxf(x, o);
}
__device__ __forceinline__ float xhalf_sum(float x) {
    float o = __shfl_xor(x, 32);
    return x + o;
}

// ---------------------------------------------------------------------------
// Fused prep: convert x -> bf16 (blocks 0..3071), transpose+convert w_qkv
// (3072..4799), transpose+convert w_out (4800..5375).
// ---------------------------------------------------------------------------
__global__ __launch_bounds__(256) void prep(const float* __restrict__ x,
                                            const float* __restrict__ w_qkv,
                                            const float* __restrict__ w_out,
                                            u16* __restrict__ xb,
                                            u16* __restrict__ wqkvT,
                                            u16* __restrict__ woutT) {
    __shared__ float T[32][33];
    const int bid = blockIdx.x;
    if (bid < 3072) {
        int i = bid * 256 + threadIdx.x;
        float4 v = reinterpret_cast<const float4*>(x)[i];
        union { u16 s[4]; int2 p; } o;
        o.s[0] = f2bf(v.x); o.s[1] = f2bf(v.y); o.s[2] = f2bf(v.z); o.s[3] = f2bf(v.w);
        reinterpret_cast<int2*>(xb)[i] = o.p;
        return;
    }
    const float* in;
    u16* out;
    int R, C, c0, r0;
    if (bid < 4800) {
        int r = bid - 3072;
        in = w_qkv; out = wqkvT; R = 768; C = 2304;
        c0 = (r % 72) * 32; r0 = (r / 72) * 32;
    } else {
        int r = bid - 4800;
        in = w_out; out = woutT; R = 768; C = 768;
        c0 = (r % 24) * 32; r0 = (r / 24) * 32;
    }
    const int tx = threadIdx.x & 31;
    const int ty = threadIdx.x >> 5;
#pragma unroll
    for (int p = 0; p < 4; ++p) {
        int ry = ty + p * 8;
        T[ry][tx] = in[(size_t)(r0 + ry) * C + c0 + tx];
    }
    __syncthreads();
#pragma unroll
    for (int p = 0; p < 4; ++p) {
        int cy = ty + p * 8;
        out[(size_t)(c0 + cy) * R + r0 + tx] = f2bf(T[tx][cy]);
    }
}

// ---------------------------------------------------------------------------
// GEMM1: qkv = x_bf16 @ w_qkv (via wqkvT); scatter into fragment-order
// Qf (scaled), Kf, Vf.  64x128 tile, reg-staged 2-buffer pipeline.
// ---------------------------------------------------------------------------
__global__ __launch_bounds__(256) void gemm_qkv(const u16* __restrict__ A,
                                                const u16* __restrict__ BT,
                                                u16* __restrict__ Qf,
                                                u16* __restrict__ Kf,
                                                u16* __restrict__ Vf) {
    __shared__ u16 As[2][64 * 32];
    __shared__ u16 Bs[2][128 * 32];
    const int tid = threadIdx.x;
    const int lane = tid & 63;
    const int w = tid >> 6;
    const int wm = w >> 1, wn = w & 1;       // wave = 32x64 of the 64x128 tile
    const int lr = lane & 15;
    const int lk = lane >> 4;
    // XCD swizzle, col-major within XCD: 144/XCD = 18 cols x 8 rows;
    // 8 consecutive blocks share one B panel; XCD owns 512 A-rows.
    const int orig = blockIdx.x >> 3;
    const int xcd = blockIdx.x & 7;
    const int col0 = (orig >> 3) * 128;                 // 0..17
    const int row0 = (xcd * 8 + (orig & 7)) * 64;
    const int sr = lane >> 2;      // staging row (16 per wave)
    const int scg = lane & 3;      // staging 16B col group

    f32x4 acc[2][4];
#pragma unroll
    for (int mi = 0; mi < 2; ++mi)
#pragma unroll
        for (int nj = 0; nj < 4; ++nj) acc[mi][nj] = (f32x4){0.f, 0.f, 0.f, 0.f};

    const u16* aSrc = A  + (size_t)(row0 + w * 16 + sr) * 768 + scg * 8;
    const u16* bSrc0 = BT + (size_t)(col0 + w * 16 + sr) * 768 + scg * 8;
    const u16* bSrc1 = BT + (size_t)(col0 + (4 + w) * 16 + sr) * 768 + scg * 8;
    u16* aDst = &As[0][(w * 16 + sr) * 32 + scg * 8];
    u16* bDst0 = &Bs[0][(w * 16 + sr) * 32 + scg * 8];
    u16* bDst1 = &Bs[0][((4 + w) * 16 + sr) * 32 + scg * 8];

#define LOADR(RA, RB0, RB1, K0)                                         \
    RA  = *reinterpret_cast<const int4*>(aSrc  + (K0));                 \
    RB0 = *reinterpret_cast<const int4*>(bSrc0 + (K0));                 \
    RB1 = *reinterpret_cast<const int4*>(bSrc1 + (K0));
#define WRITER(BUF, RA, RB0, RB1)                                       \
    *reinterpret_cast<int4*>(aDst  + (BUF) * 64 * 32)  = RA;            \
    *reinterpret_cast<int4*>(bDst0 + (BUF) * 128 * 32) = RB0;           \
    *reinterpret_cast<int4*>(bDst1 + (BUF) * 128 * 32) = RB1;
#define COMPUTE(BUF)                                                          \
    {                                                                         \
        bf16x8 af[2], bfr[4];                                                 \
        _Pragma("unroll")                                                     \
        for (int mi = 0; mi < 2; ++mi)                                        \
            af[mi] = *reinterpret_cast<const bf16x8*>(&As[BUF][(wm * 32 + mi * 16 + lr) * 32 + lk * 8]); \
        _Pragma("unroll")                                                     \
        for (int nj = 0; nj < 4; ++nj)                                        \
            bfr[nj] = *reinterpret_cast<const bf16x8*>(&Bs[BUF][(wn * 64 + nj * 16 + lr) * 32 + lk * 8]); \
        __builtin_amdgcn_s_setprio(1);                                        \
        _Pragma("unroll")                                                     \
        for (int mi = 0; mi < 2; ++mi)                                        \
            _Pragma("unroll")                                                 \
            for (int nj = 0; nj < 4; ++nj)                                    \
                acc[mi][nj] = __builtin_amdgcn_mfma_f32_16x16x32_bf16(af[mi], bfr[nj], acc[mi][nj], 0, 0, 0); \
        __builtin_amdgcn_s_setprio(0);                                        \
    }
#define BARRIER()                                                       \
    asm volatile("s_waitcnt lgkmcnt(0)" ::: "memory");                  \
    __builtin_amdgcn_sched_barrier(0);                                  \
    __builtin_amdgcn_s_barrier();

    int4 rA_a, rA_b0, rA_b1, rB_a, rB_b0, rB_b1;
    LOADR(rA_a, rA_b0, rA_b1, 0);        // tile 0
    LOADR(rB_a, rB_b0, rB_b1, 32);       // tile 1
    WRITER(0, rA_a, rA_b0, rA_b1);       // compiler waits only tile-0 loads
    BARRIER();

#pragma unroll 1
    for (int t = 0; t < 24; t += 2) {
        // even iter: compute buf0; regs B hold tile t+1; fetch t+2 into regs A
        if (t + 2 < 24) { LOADR(rA_a, rA_b0, rA_b1, (t + 2) * 32); }
        COMPUTE(0);
        WRITER(1, rB_a, rB_b0, rB_b1);   // waits tile t+1 loads only
        BARRIER();
        // odd iter: compute buf1; regs A hold tile t+2; fetch t+3 into regs B
        if (t + 3 < 24) { LOADR(rB_a, rB_b0, rB_b1, (t + 3) * 32); }
        COMPUTE(1);
        if (t + 2 < 24) { WRITER(0, rA_a, rA_b0, rA_b1); }
        BARRIER();
    }
#undef LOADR
#undef WRITER
#undef COMPUTE
#undef BARRIER

    const int which = col0 / 768;
    const int cb = col0 - which * 768;
#pragma unroll
    for (int mi = 0; mi < 2; ++mi) {
#pragma unroll
        for (int i = 0; i < 4; ++i) {
            int r = row0 + wm * 32 + mi * 16 + lk * 4 + i;
            int b = r >> 10, n = r & 1023;
#pragma unroll
            for (int nj = 0; nj < 4; ++nj) {
                int cw = cb + wn * 64 + nj * 16 + lr;
                int h = cw >> 6, d = cw & 63;
                int bh = b * 12 + h;
                float val = acc[mi][nj][i];
                if (which == 2) {
                    size_t off = ((((size_t)bh * 16 + (n >> 6)) * 4 + ((n >> 4) & 3)) * 2 + ((n >> 3) & 1)) * 512
                                 + d * 8 + (n & 7);
                    Vf[off] = f2bf(val);
                } else {
                    size_t off = ((((size_t)bh * 32 + (n >> 5)) * 4 + (d >> 4)) * 2 + ((d >> 3) & 1)) * 256
                                 + (n & 31) * 8 + (d & 7);
                    if (which == 0) Qf[off] = f2bf(val * 0.18033688f);   // 0.125*log2(e)
                    else            Kf[off] = f2bf(val);
                }
            }
        }
    }
}

// ---------------------------------------------------------------------------
// Flash attention, swapped-operand 32x32x16 MFMA, fragment-order global
// layouts -> every load is base + lane*16B.  No LDS / barriers in KV loop.
// ---------------------------------------------------------------------------
#define GETO(dt, r) ((dt) == 0 ? o0[r] : o1[r])

__global__ __launch_bounds__(256) void attn_mfma(const u16* __restrict__ Qf,
                                                 const u16* __restrict__ Kf,
                                                 const u16* __restrict__ Vf,
                                                 u16* __restrict__ attn_out) {
    __shared__ float OtM[2][64][33];
    __shared__ float Lm[2][32], Ll[2][32];
    __shared__ u16 Os[2][32][72];

    const int tid = threadIdx.x;
    const int lane = tid & 63;
    const int w = tid >> 6;
    const int qsub = w & 1;
    const int half = w >> 1;
    const int l31 = lane & 31;
    const int hi = lane >> 5;

    const int bid = blockIdx.x;
    const int lin = (bid & 7) * 96 + (bid >> 3);
    const int qt = lin & 15;
    const int bh = lin >> 4;

    const u16* Qh = Qf + (size_t)bh * 65536;
    const u16* Kh = Kf + (size_t)bh * 65536;
    const u16* Vh = Vf + (size_t)bh * 65536;

    bf16x8 qf[4];
#pragma unroll
    for (int kt = 0; kt < 4; ++kt)
        qf[kt] = *reinterpret_cast<const bf16x8*>(
            Qh + (((size_t)(qt * 2 + qsub) * 4 + kt) * 2 + hi) * 256 + l31 * 8);

    f32x16 o0 = ZERO16, o1 = ZERO16;
    float m = -1e30f, l = 0.f;

    for (int it = 0; it < 8; ++it) {
        const int kb0 = it * 4 + half * 2;
        const int kvb = it * 2 + half;

        bf16x8 kf0[4], kf1[4];
#pragma unroll
        for (int kt = 0; kt < 4; ++kt) {
            kf0[kt] = *reinterpret_cast<const bf16x8*>(
                Kh + (((size_t)kb0 * 4 + kt) * 2 + hi) * 256 + l31 * 8);
            kf1[kt] = *reinterpret_cast<const bf16x8*>(
                Kh + (((size_t)(kb0 + 1) * 4 + kt) * 2 + hi) * 256 + l31 * 8);
        }
        bf16x8 vf0[4], vf1[4];
#pragma unroll
        for (int ks = 0; ks < 4; ++ks) {
            const u16* vb = Vh + (((size_t)kvb * 4 + ks) * 2 + hi) * 512;
            vf0[ks] = *reinterpret_cast<const bf16x8*>(vb + l31 * 8);
            vf1[ks] = *reinterpret_cast<const bf16x8*>(vb + (l31 + 32) * 8);
        }

        f32x16 s0 = ZERO16, s1 = ZERO16;
        __builtin_amdgcn_s_setprio(1);
#pragma unroll
        for (int kt = 0; kt < 4; ++kt) s0 = __builtin_amdgcn_mfma_f32_32x32x16_bf16(kf0[kt], qf[kt], s0, 0, 0, 0);
#pragma unroll
        for (int kt = 0; kt < 4; ++kt) s1 = __builtin_amdgcn_mfma_f32_32x32x16_bf16(kf1[kt], qf[kt], s1, 0, 0, 0);
        __builtin_amdgcn_s_setprio(0);

        float mx[8];
#pragma unroll
        for (int i = 0; i < 8; ++i)
            mx[i] = fmaxf(fmaxf(s0[2*i], s0[2*i+1]), fmaxf(s1[2*i], s1[2*i+1]));
        float pmax = fmaxf(fmaxf(fmaxf(mx[0], mx[1]), fmaxf(mx[2], mx[3])),
                           fmaxf(fmaxf(mx[4], mx[5]), fmaxf(mx[6], mx[7])));
        pmax = xhalf_max(pmax);

        if (!__all(pmax <= m + 8.f)) {
            float mn = fmaxf(m, pmax);
            float c = __builtin_amdgcn_exp2f(m - mn);
            m = mn; l *= c;
            o0 = o0 * c; o1 = o1 * c;
        }

#pragma unroll
        for (int r = 0; r < 16; ++r) s0[r] = __builtin_amdgcn_exp2f(s0[r] - m);
#pragma unroll
        for (int r = 0; r < 16; ++r) s1[r] = __builtin_amdgcn_exp2f(s1[r] - m);
        float sm[8];
#pragma unroll
        for (int i = 0; i < 8; ++i)
            sm[i] = (s0[2*i] + s0[2*i+1]) + (s1[2*i] + s1[2*i+1]);
        float tsum = ((sm[0]+sm[1]) + (sm[2]+sm[3])) + ((sm[4]+sm[5]) + (sm[6]+sm[7]));
        l += xhalf_sum(tsum);

        bf16x8 pb[4];
#define PACK_GROUP(S, G, OUT)                                           \
        {                                                               \
            u32 X0 = cvtpk(S[8*(G)+0], S[8*(G)+1]);                     \
            u32 X1 = cvtpk(S[8*(G)+2], S[8*(G)+3]);                     \
            u32 Y0 = cvtpk(S[8*(G)+4], S[8*(G)+5]);                     \
            u32 Y1 = cvtpk(S[8*(G)+6], S[8*(G)+7]);                     \
            u32 X0s = (u32)__shfl_xor((int)X0, 32);                     \
            u32 X1s = (u32)__shfl_xor((int)X1, 32);                     \
            u32 Y0s = (u32)__shfl_xor((int)Y0, 32);                     \
            u32 Y1s = (u32)__shfl_xor((int)Y1, 32);                     \
            union { u32 u[4]; bf16x8 v; } pk_;                          \
            pk_.u[0] = hi ? Y0s : X0;                                   \
            pk_.u[1] = hi ? Y1s : X1;                                   \
            pk_.u[2] = hi ? Y0 : X0s;                                   \
            pk_.u[3] = hi ? Y1 : X1s;                                   \
            OUT = pk_.v;                                                \
        }
        PACK_GROUP(s0, 0, pb[0]);
        PACK_GROUP(s0, 1, pb[1]);
        PACK_GROUP(s1, 0, pb[2]);
        PACK_GROUP(s1, 1, pb[3]);
#undef PACK_GROUP

        __builtin_amdgcn_s_setprio(1);
#pragma unroll
        for (int ks = 0; ks < 4; ++ks) {
            o0 = __builtin_amdgcn_mfma_f32_32x32x16_bf16(vf0[ks], pb[ks], o0, 0, 0, 0);
            o1 = __builtin_amdgcn_mfma_f32_32x32x16_bf16(vf1[ks], pb[ks], o1, 0, 0, 0);
        }
        __builtin_amdgcn_s_setprio(0);
    }

    if (half == 1) {
#pragma unroll
        for (int dt = 0; dt < 2; ++dt)
#pragma unroll
            for (int r = 0; r < 16; ++r)
                OtM[qsub][dt * 32 + (r & 3) + 8 * (r >> 2) + 4 * hi][l31] = GETO(dt, r);
        Lm[qsub][l31] = m;
        Ll[qsub][l31] = l;
    }
    __syncthreads();
    if (half == 0) {
        float m2 = Lm[qsub][l31], l2 = Ll[qsub][l31];
        float mn = fmaxf(m, m2);
        float a = __builtin_amdgcn_exp2f(m - mn);
        float bsc = __builtin_amdgcn_exp2f(m2 - mn);
        float lm = l * a + l2 * bsc;
        float inv = 1.0f / lm;
        float av = a * inv, bv = bsc * inv;
#pragma unroll
        for (int dt = 0; dt < 2; ++dt)
#pragma unroll
            for (int rq = 0; rq < 4; ++rq) {
                int d0 = dt * 32 + 8 * rq + 4 * hi;
                float v0 = GETO(dt, rq * 4 + 0) * av + OtM[qsub][d0 + 0][l31] * bv;
                float v1 = GETO(dt, rq * 4 + 1) * av + OtM[qsub][d0 + 1][l31] * bv;
                float v2 = GETO(dt, rq * 4 + 2) * av + OtM[qsub][d0 + 2][l31] * bv;
                float v3 = GETO(dt, rq * 4 + 3) * av + OtM[qsub][d0 + 3][l31] * bv;
                uint2 pr;
                pr.x = cvtpk(v0, v1);
                pr.y = cvtpk(v2, v3);
                *reinterpret_cast<uint2*>(&Os[qsub][l31][d0]) = pr;
            }
    }
    __syncthreads();

    const int b = bh / 12, h = bh % 12;
#pragma unroll
    for (int it2 = 0; it2 < 2; ++it2) {
        int idx = tid + it2 * 256;
        int token = idx >> 3;
        int chunk = idx & 7;
        int4 v = *reinterpret_cast<const int4*>(&Os[token >> 5][token & 31][chunk * 8]);
        *reinterpret_cast<int4*>(&attn_out[((size_t)(b * 1024 + qt * 64 + token)) * 768 + h * 64 + chunk * 8]) = v;
    }
}

// ---------------------------------------------------------------------------
// GEMM2: out = attn_bf16 @ w_out (via woutT) + b_out.  64x128 tile,
// reg-staged 2-buffer pipeline.
// ---------------------------------------------------------------------------
__global__ __launch_bounds__(256) void gemm_out(const u16* __restrict__ A,
                                                const u16* __restrict__ BT,
                                                const float* __restrict__ bias,
                                                float* __restrict__ out) {
    __shared__ u16 As[2][64 * 32];
    __shared__ u16 Bs[2][128 * 32];
    const int tid = threadIdx.x;
    const int lane = tid & 63;
    const int w = tid >> 6;
    const int wm = w >> 1, wn = w & 1;
    const int lr = lane & 15;
    const int lk = lane >> 4;
    // XCD swizzle, col-major within XCD: 48/XCD = 6 cols x 8 rows
    const int orig = blockIdx.x >> 3;
    const int xcd = blockIdx.x & 7;
    const int col0 = (orig >> 3) * 128;                 // 0..5
    const int row0 = (xcd * 8 + (orig & 7)) * 64;
    const int sr = lane >> 2;
    const int scg = lane & 3;

    f32x4 acc[2][4];
#pragma unroll
    for (int mi = 0; mi < 2; ++mi)
#pragma unroll
        for (int nj = 0; nj < 4; ++nj) acc[mi][nj] = (f32x4){0.f, 0.f, 0.f, 0.f};

    const u16* aSrc = A  + (size_t)(row0 + w * 16 + sr) * 768 + scg * 8;
    const u16* bSrc0 = BT + (size_t)(col0 + w * 16 + sr) * 768 + scg * 8;
    const u16* bSrc1 = BT + (size_t)(col0 + (4 + w) * 16 + sr) * 768 + scg * 8;
    u16* aDst = &As[0][(w * 16 + sr) * 32 + scg * 8];
    u16* bDst0 = &Bs[0][(w * 16 + sr) * 32 + scg * 8];
    u16* bDst1 = &Bs[0][((4 + w) * 16 + sr) * 32 + scg * 8];

#define LOADR(RA, RB0, RB1, K0)                                         \
    RA  = *reinterpret_cast<const int4*>(aSrc  + (K0));                 \
    RB0 = *reinterpret_cast<const int4*>(bSrc0 + (K0));                 \
    RB1 = *reinterpret_cast<const int4*>(bSrc1 + (K0));
#define WRITER(BUF, RA, RB0, RB1)                                       \
    *reinterpret_cast<int4*>(aDst  + (BUF) * 64 * 32)  = RA;            \
    *reinterpret_cast<int4*>(bDst0 + (BUF) * 128 * 32) = RB0;           \
    *reinterpret_cast<int4*>(bDst1 + (BUF) * 128 * 32) = RB1;
#define COMPUTE(BUF)                                                          \
    {                                                                         \
        bf16x8 af[2], bfr[4];                                                 \
        _Pragma("unroll")                                                     \
        for (int mi = 0; mi < 2; ++mi)                                        \
            af[mi] = *reinterpret_cast<const bf16x8*>(&As[BUF][(wm * 32 + mi * 16 + lr) * 32 + lk * 8]); \
        _Pragma("unroll")                                                     \
        for (int nj = 0; nj < 4; ++nj)                                        \
            bfr[nj] = *reinterpret_cast<const bf16x8*>(&Bs[BUF][(wn * 64 + nj * 16 + lr) * 32 + lk * 8]); \
        __builtin_amdgcn_s_setprio(1);                                        \
        _Pragma("unroll")                                                     \
        for (int mi = 0; mi < 2; ++mi)                                        \
            _Pragma("unroll")                                                 \
            for (int nj = 0; nj < 4; ++nj)                                    \
                acc[mi][nj] = __builtin_amdgcn_mfma_f32_16x16x32_bf16(af[mi], bfr[nj], acc[mi][nj], 0, 0, 0); \
        __builtin_amdgcn_s_setprio(0);                                        \
    }
#define BARRIER()                                                       \
    asm volatile("s_waitcnt lgkmcnt(0)" ::: "memory");                  \
    __builtin_amdgcn_sched_barrier(0);                                  \
    __builtin_amdgcn_s_barrier();

    int4 rA_a, rA_b0, rA_b1, rB_a, rB_b0, rB_b1;
    LOADR(rA_a, rA_b0, rA_b1, 0);
    LOADR(rB_a, rB_b0, rB_b1, 32);
    WRITER(0, rA_a, rA_b0, rA_b1);
    BARRIER();

#pragma unroll 1
    for (int t = 0; t < 24; t += 2) {
        if (t + 2 < 24) { LOADR(rA_a, rA_b0, rA_b1, (t + 2) * 32); }
        COMPUTE(0);
        WRITER(1, rB_a, rB_b0, rB_b1);
        BARRIER();
        if (t + 3 < 24) { LOADR(rB_a, rB_b0, rB_b1, (t + 3) * 32); }
        COMPUTE(1);
        if (t + 2 < 24) { WRITER(0, rA_a, rA_b0, rA_b1); }
        BARRIER();
    }
#undef LOADR
#undef WRITER
#undef COMPUTE
#undef BARRIER

#pragma unroll
    for (int mi = 0; mi < 2; ++mi)
#pragma unroll
        for (int i = 0; i < 4; ++i) {
            int r = row0 + wm * 32 + mi * 16 + lk * 4 + i;
#pragma unroll
            for (int nj = 0; nj < 4; ++nj) {
                int c = col0 + wn * 64 + nj * 16 + lr;
                out[(size_t)r * 768 + c] = acc[mi][nj][i] + bias[c];
            }
        }
}

// ---------------------------------------------------------------------------
extern "C" void kernel_launch(void* const* d_in, const int* in_sizes, int n_in,
                              void* d_out, int out_size, void* d_ws, size_t ws_size,
                              hipStream_t stream) {
    const float* x     = (const float*)d_in[0];
    const float* w_qkv = (const float*)d_in[1];
    const float* w_out = (const float*)d_in[2];
    const float* b_out = (const float*)d_in[3];
    float* out = (float*)d_out;

    u16* ws = (u16*)d_ws;
    const size_t n_x = (size_t)4096 * 768;
    u16* xb     = ws;
    u16* wqkvT  = xb + n_x;
    u16* woutT  = wqkvT + (size_t)2304 * 768;
    u16* Qfr    = woutT + (size_t)768 * 768;      // fragment-order, 65536/bh
    u16* Kfr    = Qfr + n_x;
    u16* Vfr    = Kfr + n_x;
    u16* attnb  = Vfr + n_x;

    prep<<<5376, 256, 0, stream>>>(x, w_qkv, w_out, xb, wqkvT, woutT);
    gemm_qkv<<<1152, 256, 0, stream>>>(xb, wqkvT, Qfr, Kfr, Vfr);
    attn_mfma<<<768, 256, 0, stream>>>(Qfr, Kfr, Vfr, attnb);
    gemm_out<<<384, 256, 0, stream>>>(attnb, woutT, b_out, out);
}